// Round 5
// baseline (177.825 us; speedup 1.0000x reference)
//
#include <hip/hip_runtime.h>
#include <hip/hip_bf16.h>
#include <type_traits>

// Problem constants
constexpr int Bc = 2, Hc = 64, Wc = 128, Cc = 256;
constexpr int HEADS = 8, KPT = 9, HIDDEN = 1024;
constexpr int HD = Cc / HEADS;           // 32
constexpr int NPIX = Hc * Wc;            // 8192
constexpr int Mrows = Bc * NPIX;         // 16384
constexpr int NQKV = 512;                // 256 (v) + 144 (off) + 72 (attn) padded to 512

typedef __attribute__((ext_vector_type(4))) float f32x4;
typedef __attribute__((ext_vector_type(8))) short bf16x8;

__device__ __forceinline__ float bf2f(unsigned short u) {
    union { unsigned int i; float f; } c; c.i = ((unsigned int)u) << 16; return c.f;
}
__device__ __forceinline__ unsigned short f2bf(float f) {
    __hip_bfloat16 h = __float2bfloat16(f);
    return *reinterpret_cast<unsigned short*>(&h);
}
__device__ __forceinline__ float gelu_exact(float x) {
    return 0.5f * x * (1.0f + erff(x * 0.70710678118654752f));
}
__device__ __forceinline__ void gl2lds16(const void* g, void* l) {
    __builtin_amdgcn_global_load_lds(
        (const __attribute__((address_space(1))) unsigned int*)g,
        (__attribute__((address_space(3))) unsigned int*)l, 16, 0, 0);
}

// ---------------- LayerNorm over C=256, one row per 256-thread block ----------------
template<typename TO>
__global__ __launch_bounds__(256) void ln_kernel(const float* __restrict__ in,
        const float* __restrict__ g, const float* __restrict__ b,
        TO* __restrict__ out) {
    const int r = blockIdx.x;
    const int t = threadIdx.x;
    const size_t base = (size_t)r * Cc;
    float val = in[base + t];
    float s = val, s2 = val * val;
    #pragma unroll
    for (int o = 32; o > 0; o >>= 1) { s += __shfl_down(s, o); s2 += __shfl_down(s2, o); }
    __shared__ float ps[4], ps2[4];
    if ((t & 63) == 0) { ps[t >> 6] = s; ps2[t >> 6] = s2; }
    __syncthreads();
    const float ts  = ps[0] + ps[1] + ps[2] + ps[3];
    const float ts2 = ps2[0] + ps2[1] + ps2[2] + ps2[3];
    const float mean = ts * (1.0f / Cc);
    const float var  = ts2 * (1.0f / Cc) - mean * mean;
    const float rstd = rsqrtf(var + 1e-5f);
    const float v = (val - mean) * rstd * g[t] + b[t];
    if constexpr (std::is_same<TO, float>::value) out[base + t] = v;
    else out[base + t] = f2bf(v);
}

// ---------------- Weight prep: f32 [K,N] -> bf16 [N,K] (transposed), QKV fused+padded ----
// Also transposes depthwise weights [1024][9] -> [9][1024] f32 for coalesced loads.
__global__ __launch_bounds__(256) void prep_weights(
        const float* __restrict__ w_v, const float* __restrict__ b_v,
        const float* __restrict__ w_off, const float* __restrict__ b_off,
        const float* __restrict__ w_attn, const float* __restrict__ b_attn,
        const float* __restrict__ w_out, const float* __restrict__ w1,
        const float* __restrict__ w2, const float* __restrict__ w_dw,
        unsigned short* __restrict__ qkvT, float* __restrict__ qkvB,
        unsigned short* __restrict__ woutT, unsigned short* __restrict__ w1T,
        unsigned short* __restrict__ w2T, float* __restrict__ wdwT) {
    const int blk = blockIdx.x;
    const int t = threadIdx.x;
    if (blk < NQKV) {                      // qkvT row n, K=256
        const int n = blk;
        float val = 0.0f;
        if (n < 256)       val = w_v[t * 256 + n];
        else if (n < 400)  val = w_off[t * 144 + (n - 256)];
        else if (n < 472)  val = w_attn[t * 72 + (n - 400)];
        qkvT[n * 256 + t] = f2bf(val);
        if (t == 0) {
            float bv = 0.0f;
            if (n < 256)      bv = b_v[n];
            else if (n < 400) bv = b_off[n - 256];
            else if (n < 472) bv = b_attn[n - 400];
            qkvB[n] = bv;
        }
    } else if (blk < NQKV + 256) {         // woutT row n, K=256
        const int n = blk - NQKV;
        woutT[n * 256 + t] = f2bf(w_out[t * 256 + n]);
    } else if (blk < NQKV + 256 + 1024) {  // w1T row n, K=256
        const int n = blk - (NQKV + 256);
        w1T[n * 256 + t] = f2bf(w1[t * 1024 + n]);
    } else if (blk < NQKV + 256 + 1024 + 256) { // w2T row n, K=1024
        const int n = blk - (NQKV + 256 + 1024);
        #pragma unroll
        for (int k = t; k < 1024; k += 256)
            w2T[n * 1024 + k] = f2bf(w2[k * 256 + n]);
    } else {                               // wdwT row j (9 rows)
        const int j = blk - (NQKV + 256 + 1024 + 256);
        #pragma unroll
        for (int c = t; c < HIDDEN; c += 256)
            wdwT[j * HIDDEN + c] = w_dw[c * 9 + j];
    }
}

// ---------------- bf16 MFMA GEMM: Out[M,N] = A[M,K] @ BT[N,K]^T + bias ----------------
// Tile 128 x BN, BK=64, 256 threads (4 waves, 2x2 wave grid), 16x16x32 bf16 MFMA.
// Grid: blockIdx.x = row panel (fastest) so the col-blocks of one row panel land on the
// SAME XCD (ids differ by Mrows/128=128, 128%8==0) -> A panel fetched by one L2 only.
// K-loop LDS: [rows][64] bf16, XOR swizzle byte^=((row&7)<<4) via pre-swizzled source.
// Epilogue: C-tile staged in (now dead) LDS, then streamed out with dwordx4 stores.
template<int BN, bool GELU, bool RESID, typename TO>
__global__ __launch_bounds__(256) void mfma_gemm(
        const unsigned short* __restrict__ A,   // [M,K] bf16
        const unsigned short* __restrict__ BT,  // [N,K] bf16
        const float* __restrict__ bias,         // [N]
        const float* __restrict__ resid,        // [M,N] f32 (if RESID)
        TO* __restrict__ Out,                   // [M,N]
        int N, int K) {
    constexpr int NFR = BN / 32;                // B fragments per wave (128->4, 64->2)
    // 32 KB serves both: K-loop staging (A 16K + B up to 16K) and epilogue C-tile
    // (128 rows x 256 B: bf16 BN=128 or f32 BN=64).
    __shared__ __align__(16) char lds[32768];
    unsigned short* As = (unsigned short*)lds;
    unsigned short* Bs = (unsigned short*)(lds + 16384);
    const int t = threadIdx.x;
    const int w = t >> 6;
    const int l = t & 63;
    const int row0 = blockIdx.x * 128;
    const int col0 = blockIdx.y * BN;
    const int wr = (w >> 1) * 64;               // wave row offset in tile
    const int wc = (w & 1) * (BN / 2);          // wave col offset in tile

    // staging geometry: chunk = 8 rows x 64 cols (1024 B); lane l -> row c*8+l/8,
    // 16B slot (l%8); source slot is XOR-swizzled so LDS holds swizzled layout.
    const int srow = l >> 3;
    const int selem = ((l & 7) ^ srow) * 8;     // element offset of this lane's 16B

    f32x4 acc[4][NFR] = {};

    for (int k0 = 0; k0 < K; k0 += 64) {
        #pragma unroll
        for (int i = 0; i < 4; ++i) {           // A tile: 16 chunks, 4 per wave
            const int c = w + i * 4;
            const int row = c * 8 + srow;
            gl2lds16(A + (size_t)(row0 + row) * K + k0 + selem, As + c * 512);
        }
        #pragma unroll
        for (int i = 0; i < NFR; ++i) {         // B tile: BN/8 chunks
            const int c = w + i * 4;
            const int row = c * 8 + srow;
            gl2lds16(BT + (size_t)(col0 + row) * K + k0 + selem, Bs + c * 512);
        }
        asm volatile("s_waitcnt vmcnt(0)" ::: "memory");
        __syncthreads();
        #pragma unroll
        for (int ks = 0; ks < 2; ++ks) {
            const int kb = ks * 64 + (l >> 4) * 16;   // byte offset within 128B row
            bf16x8 af[4], bfr[NFR];
            #pragma unroll
            for (int mi = 0; mi < 4; ++mi) {
                const int row = wr + mi * 16 + (l & 15);
                af[mi] = *(const bf16x8*)((const char*)As + row * 128 + (kb ^ ((row & 7) << 4)));
            }
            #pragma unroll
            for (int ni = 0; ni < NFR; ++ni) {
                const int row = wc + ni * 16 + (l & 15);
                bfr[ni] = *(const bf16x8*)((const char*)Bs + row * 128 + (kb ^ ((row & 7) << 4)));
            }
            #pragma unroll
            for (int mi = 0; mi < 4; ++mi)
                #pragma unroll
                for (int ni = 0; ni < NFR; ++ni)
                    acc[mi][ni] = __builtin_amdgcn_mfma_f32_16x16x32_bf16(
                        af[mi], bfr[ni], acc[mi][ni], 0, 0, 0);
        }
        __syncthreads();
    }

    // ---- epilogue phase 1: stage C-tile into LDS (256 B per row, row-XOR swizzle) ----
    // MFMA C/D layout: col=l&15, row=(l>>4)*4+reg (guide §3, m89-verified)
    const int lrow = (l >> 4) * 4;
    const int lcol = l & 15;
    #pragma unroll
    for (int ni = 0; ni < NFR; ++ni) {
        const int col = wc + ni * 16 + lcol;            // tile-relative col
        const float bb = bias[col0 + col];
        #pragma unroll
        for (int mi = 0; mi < 4; ++mi) {
            #pragma unroll
            for (int r = 0; r < 4; ++r) {
                const int row = wr + mi * 16 + lrow + r;
                float v = acc[mi][ni][r] + bb;
                if constexpr (GELU) v = gelu_exact(v);
                if constexpr (std::is_same<TO, unsigned short>::value) {
                    *(unsigned short*)(lds + row * 256 + ((col * 2) ^ ((row & 7) << 4))) = f2bf(v);
                } else {
                    *(float*)(lds + row * 256 + ((col * 4) ^ ((row & 7) << 4))) = v;
                }
            }
        }
    }
    __syncthreads();
    // ---- epilogue phase 2: wide coalesced write-back (8 x 16B per thread) ----
    const int rr = t >> 1;                    // tile row (128 rows, 2 threads each)
    const int hf = t & 1;                     // which 128-byte half of the row
    if constexpr (std::is_same<TO, unsigned short>::value) {
        unsigned short* obase = Out + (size_t)(row0 + rr) * N + col0;
        #pragma unroll
        for (int i = 0; i < 8; ++i) {
            const int bo = hf * 128 + i * 16;
            const int4 val = *(const int4*)(lds + rr * 256 + (bo ^ ((rr & 7) << 4)));
            *(int4*)(obase + bo / 2) = val;
        }
    } else {
        float* obase = (float*)Out + (size_t)(row0 + rr) * N + col0;
        const float* rbase = RESID ? (resid + (size_t)(row0 + rr) * N + col0) : nullptr;
        #pragma unroll
        for (int i = 0; i < 8; ++i) {
            const int bo = hf * 128 + i * 16;
            float4 val = *(const float4*)(lds + rr * 256 + (bo ^ ((rr & 7) << 4)));
            if constexpr (RESID) {
                const float4 rv = *(const float4*)(rbase + bo / 4);
                val.x += rv.x; val.y += rv.y; val.z += rv.z; val.w += rv.w;
            }
            *(float4*)(obase + bo / 4) = val;
        }
    }
}

// ---------------- Deformable sampling + softmax + aggregation (bf16 in/out) ----------------
// F = fused QKV buffer [M, 512]: cols 0-255 v, 256-399 offsets, 400-471 attn logits.
__global__ __launch_bounds__(256) void sample_kernel(const unsigned short* __restrict__ F,
        const float* __restrict__ refp, unsigned short* __restrict__ agg) {
    const int m = blockIdx.x;
    const int b = m / NPIX;
    const int pix = m - b * NPIX;
    const int t = threadIdx.x;
    __shared__ int   s_i0[72], s_i1[72], s_i2[72], s_i3[72];
    __shared__ float s_w0[72], s_w1[72], s_w2[72], s_w3[72];
    __shared__ float s_lg[72];
    if (t < 72) {
        const int head = t / 9, k = t - head * 9;
        const size_t fb = (size_t)m * NQKV;
        const float ox = bf2f(F[fb + 256 + head * 18 + k * 2 + 0]);
        const float oy = bf2f(F[fb + 256 + head * 18 + k * 2 + 1]);
        const float rx = refp[((size_t)pix * KPT + k) * 2 + 0];
        const float ry = refp[((size_t)pix * KPT + k) * 2 + 1];
        const float cx = (rx + ox + 1.0f) * 0.5f * (Wc - 1);
        const float cy = (ry + oy + 1.0f) * 0.5f * (Hc - 1);
        const float fx = floorf(cx), fy = floorf(cy);
        const float wx = cx - fx, wy = cy - fy;
        const int x0 = min(max((int)fx, 0), Wc - 1);
        const int x1 = min(max((int)fx + 1, 0), Wc - 1);
        const int y0 = min(max((int)fy, 0), Hc - 1);
        const int y1 = min(max((int)fy + 1, 0), Hc - 1);
        s_i0[t] = y0 * Wc + x0; s_i1[t] = y0 * Wc + x1;
        s_i2[t] = y1 * Wc + x0; s_i3[t] = y1 * Wc + x1;
        s_w0[t] = (1.0f - wy) * (1.0f - wx); s_w1[t] = (1.0f - wy) * wx;
        s_w2[t] = wy * (1.0f - wx);          s_w3[t] = wy * wx;
        s_lg[t] = bf2f(F[fb + 400 + t]);
    }
    __syncthreads();
    if (t < 72) {
        const int head = t / 9;
        float mx = -1e30f;
        #pragma unroll
        for (int k = 0; k < 9; ++k) mx = fmaxf(mx, s_lg[head * 9 + k]);
        float sm = 0.0f;
        #pragma unroll
        for (int k = 0; k < 9; ++k) sm += __expf(s_lg[head * 9 + k] - mx);
        const float a = __expf(s_lg[t] - mx) / sm;
        s_w0[t] *= a; s_w1[t] *= a; s_w2[t] *= a; s_w3[t] *= a;
    }
    __syncthreads();
    const int head = t >> 5, d = t & 31;
    const unsigned short* vb = F + (size_t)b * NPIX * NQKV + head * HD + d;
    float acc = 0.0f;
    #pragma unroll
    for (int k = 0; k < 9; ++k) {
        const int hk = head * 9 + k;
        acc += bf2f(vb[(size_t)s_i0[hk] * NQKV]) * s_w0[hk]
             + bf2f(vb[(size_t)s_i1[hk] * NQKV]) * s_w1[hk]
             + bf2f(vb[(size_t)s_i2[hk] * NQKV]) * s_w2[hk]
             + bf2f(vb[(size_t)s_i3[hk] * NQKV]) * s_w3[hk];
    }
    agg[(size_t)m * Cc + t] = f2bf(acc);
}

// ---------------- Depthwise 3x3 conv (circular W, zero H) + GELU, bf16 in/out ----------------
// Quad-of-pixels per block: each block computes 4 consecutive x positions for all 1024
// channels; thread t owns channels [4t,4t+4) for all 4 outputs. Loads 3 rows x 6 cols
// (18 independent ushort4 per thread) -> 2x less L2 traffic + 4x ILP vs 1-pixel blocks.
__global__ __launch_bounds__(256) void dwconv_kernel(const unsigned short* __restrict__ h,
        const float* __restrict__ wdwT, const float* __restrict__ bdw,
        unsigned short* __restrict__ h2) {
    constexpr int NQ = 4;                     // x-positions per block
    constexpr int nblk = Mrows / NQ;          // 4096
    const int bid = blockIdx.x;
    const int qi = (bid & 7) * (nblk / 8) + (bid >> 3);   // XCD-chunked swizzle (4096 % 8 == 0)
    const int m0 = qi * NQ;                   // quad never crosses a row (Wc % NQ == 0)
    const int b = m0 / NPIX;
    const int pix0 = m0 - b * NPIX;
    const int y = pix0 / Wc, x0 = pix0 - y * Wc;
    const int t = threadIdx.x;
    const int c0 = t * 4;

    float wreg[9][4];
    #pragma unroll
    for (int j = 0; j < 9; ++j) {
        const float4 wv = *reinterpret_cast<const float4*>(wdwT + j * HIDDEN + c0);
        wreg[j][0] = wv.x; wreg[j][1] = wv.y; wreg[j][2] = wv.z; wreg[j][3] = wv.w;
    }

    float acc[NQ][4] = {};
    #pragma unroll
    for (int dy = -1; dy <= 1; ++dy) {
        const int yy = y + dy;
        if (yy < 0 || yy >= Hc) continue;     // zero pad along height (block-uniform branch)
        const size_t rowbase = ((size_t)b * NPIX + (size_t)yy * Wc) * HIDDEN + c0;
        #pragma unroll
        for (int j = 0; j < NQ + 2; ++j) {    // columns x0-1 .. x0+NQ (circular)
            const int xx = (x0 + j - 1 + Wc) & (Wc - 1);
            const ushort4 hv = *reinterpret_cast<const ushort4*>(h + rowbase + (size_t)xx * HIDDEN);
            const float f0 = bf2f(hv.x), f1 = bf2f(hv.y), f2 = bf2f(hv.z), f3 = bf2f(hv.w);
            #pragma unroll
            for (int q = 0; q < NQ; ++q) {
                if (q >= j - 2 && q <= j) {   // folds to constants after unroll
                    const int wj = (dy + 1) * 3 + (j - q);
                    acc[q][0] += f0 * wreg[wj][0];
                    acc[q][1] += f1 * wreg[wj][1];
                    acc[q][2] += f2 * wreg[wj][2];
                    acc[q][3] += f3 * wreg[wj][3];
                }
            }
        }
    }
    const float4 bb = *reinterpret_cast<const float4*>(bdw + c0);
    #pragma unroll
    for (int q = 0; q < NQ; ++q) {
        ushort4 o;
        o.x = f2bf(gelu_exact(acc[q][0] + bb.x));
        o.y = f2bf(gelu_exact(acc[q][1] + bb.y));
        o.z = f2bf(gelu_exact(acc[q][2] + bb.z));
        o.w = f2bf(gelu_exact(acc[q][3] + bb.w));
        *reinterpret_cast<ushort4*>(h2 + (size_t)(m0 + q) * HIDDEN + c0) = o;
    }
}

extern "C" void kernel_launch(void* const* d_in, const int* in_sizes, int n_in,
                              void* d_out, int out_size, void* d_ws, size_t ws_size,
                              hipStream_t stream) {
    const float* x      = (const float*)d_in[0];
    const float* refp   = (const float*)d_in[1];
    const float* ln1_g  = (const float*)d_in[2];
    const float* ln1_b  = (const float*)d_in[3];
    const float* w_v    = (const float*)d_in[4];
    const float* b_v    = (const float*)d_in[5];
    const float* w_off  = (const float*)d_in[6];
    const float* b_off  = (const float*)d_in[7];
    const float* w_attn = (const float*)d_in[8];
    const float* b_attn = (const float*)d_in[9];
    const float* w_out  = (const float*)d_in[10];
    const float* b_out  = (const float*)d_in[11];
    const float* ln2_g  = (const float*)d_in[12];
    const float* ln2_b  = (const float*)d_in[13];
    const float* w1     = (const float*)d_in[14];
    const float* b1     = (const float*)d_in[15];
    const float* w_dw   = (const float*)d_in[16];
    const float* b_dw   = (const float*)d_in[17];
    const float* w2     = (const float*)d_in[18];
    const float* b2     = (const float*)d_in[19];
    float* out = (float*)d_out;

    // Workspace layout (bytes); lifetimes make the overlaps safe:
    //  [0,  8M): xn -> agg -> y          (bf16 [M,256], sequential reuse)
    //  [8, 24M): F fused qkv (bf16 [M,512]) — dead after sample_kernel
    //  [8, 40M): h (bf16 [M,1024])       — written after F is dead
    //  [40,72M): h2 (bf16 [M,1024])
    //  [72M,..): transposed bf16 weights + wdwT + fused qkv bias
    char* wsb = (char*)d_ws;
    unsigned short* xnR = (unsigned short*)(wsb);
    unsigned short* F   = (unsigned short*)(wsb + (8ull  << 20));
    unsigned short* h   = (unsigned short*)(wsb + (8ull  << 20));
    unsigned short* h2  = (unsigned short*)(wsb + (40ull << 20));
    size_t woff = 72ull << 20;
    unsigned short* qkvT = (unsigned short*)(wsb + woff); woff += (size_t)NQKV * 256 * 2;
    unsigned short* woutT= (unsigned short*)(wsb + woff); woff += 256 * 256 * 2;
    unsigned short* w1T  = (unsigned short*)(wsb + woff); woff += 1024 * 256 * 2;
    unsigned short* w2T  = (unsigned short*)(wsb + woff); woff += 256 * 1024 * 2;
    float*          wdwT = (float*)(wsb + woff);          woff += 9 * 1024 * 4;
    float*          qkvB = (float*)(wsb + woff);

    // 0. weight transpose/convert (independent of activations)
    prep_weights<<<NQKV + 256 + 1024 + 256 + 9, 256, 0, stream>>>(
        w_v, b_v, w_off, b_off, w_attn, b_attn, w_out, w1, w2, w_dw,
        qkvT, qkvB, woutT, w1T, w2T, wdwT);
    // 1. LN1 -> xn (bf16)
    ln_kernel<unsigned short><<<Mrows, 256, 0, stream>>>(x, ln1_g, ln1_b, xnR);
    // 2. fused QKV GEMM: F = xn @ [w_v|w_off|w_attn] + bias  (bf16 out)
    mfma_gemm<128, false, false, unsigned short><<<dim3(Mrows / 128, NQKV / 128), 256, 0, stream>>>(
        xnR, qkvT, qkvB, nullptr, F, NQKV, 256);
    // 3. deformable sampling + softmax + aggregation -> agg (reuses xn region)
    sample_kernel<<<Mrows, 256, 0, stream>>>(F, refp, xnR);
    // 4. x2 = x + agg @ w_out + b_out -> d_out (f32)
    mfma_gemm<64, false, true, float><<<dim3(Mrows / 128, 256 / 64), 256, 0, stream>>>(
        xnR, woutT, b_out, x, out, 256, 256);
    // 5. LN2 -> y (bf16, reuses xn region)
    ln_kernel<unsigned short><<<Mrows, 256, 0, stream>>>(out, ln2_g, ln2_b, xnR);
    // 6. h = gelu(y @ w1 + b1) (bf16)
    mfma_gemm<128, true, false, unsigned short><<<dim3(Mrows / 128, 1024 / 128), 256, 0, stream>>>(
        xnR, w1T, b1, nullptr, h, 1024, 256);
    // 7. depthwise conv + gelu -> h2 (bf16)
    dwconv_kernel<<<Mrows / 4, 256, 0, stream>>>(h, wdwT, b_dw, h2);
    // 8. out = x2 + h2 @ w2 + b2 (f32, in-place residual)
    mfma_gemm<64, false, true, float><<<dim3(Mrows / 128, 256 / 64), 256, 0, stream>>>(
        h2, w2T, b2, out, out, 256, 1024);
}

// Round 6
// 172.723 us; speedup vs baseline: 1.0295x; 1.0295x over previous
//
#include <hip/hip_runtime.h>
#include <hip/hip_bf16.h>
#include <type_traits>

// Problem constants
constexpr int Bc = 2, Hc = 64, Wc = 128, Cc = 256;
constexpr int HEADS = 8, KPT = 9, HIDDEN = 1024;
constexpr int HD = Cc / HEADS;           // 32
constexpr int NPIX = Hc * Wc;            // 8192
constexpr int Mrows = Bc * NPIX;         // 16384
constexpr int NQKV = 512;                // 256 (v) + 144 (off) + 72 (attn) padded to 512

typedef __attribute__((ext_vector_type(4))) float f32x4;
typedef __attribute__((ext_vector_type(8))) short bf16x8;

__device__ __forceinline__ float bf2f(unsigned short u) {
    union { unsigned int i; float f; } c; c.i = ((unsigned int)u) << 16; return c.f;
}
__device__ __forceinline__ unsigned short f2bf(float f) {
    __hip_bfloat16 h = __float2bfloat16(f);
    return *reinterpret_cast<unsigned short*>(&h);
}
__device__ __forceinline__ float gelu_exact(float x) {
    return 0.5f * x * (1.0f + erff(x * 0.70710678118654752f));
}
__device__ __forceinline__ void gl2lds16(const void* g, void* l) {
    __builtin_amdgcn_global_load_lds(
        (const __attribute__((address_space(1))) unsigned int*)g,
        (__attribute__((address_space(3))) unsigned int*)l, 16, 0, 0);
}

// ---------------- LayerNorm over C=256, one row per 256-thread block ----------------
template<typename TO>
__global__ __launch_bounds__(256) void ln_kernel(const float* __restrict__ in,
        const float* __restrict__ g, const float* __restrict__ b,
        TO* __restrict__ out) {
    const int r = blockIdx.x;
    const int t = threadIdx.x;
    const size_t base = (size_t)r * Cc;
    float val = in[base + t];
    float s = val, s2 = val * val;
    #pragma unroll
    for (int o = 32; o > 0; o >>= 1) { s += __shfl_down(s, o); s2 += __shfl_down(s2, o); }
    __shared__ float ps[4], ps2[4];
    if ((t & 63) == 0) { ps[t >> 6] = s; ps2[t >> 6] = s2; }
    __syncthreads();
    const float ts  = ps[0] + ps[1] + ps[2] + ps[3];
    const float ts2 = ps2[0] + ps2[1] + ps2[2] + ps2[3];
    const float mean = ts * (1.0f / Cc);
    const float var  = ts2 * (1.0f / Cc) - mean * mean;
    const float rstd = rsqrtf(var + 1e-5f);
    const float v = (val - mean) * rstd * g[t] + b[t];
    if constexpr (std::is_same<TO, float>::value) out[base + t] = v;
    else out[base + t] = f2bf(v);
}

// ---------------- Weight prep: f32 [K,N] -> bf16 [N,K] (transposed), QKV fused+padded ----
// Also transposes depthwise weights [1024][9] -> [9][1024] f32 for coalesced loads.
__global__ __launch_bounds__(256) void prep_weights(
        const float* __restrict__ w_v, const float* __restrict__ b_v,
        const float* __restrict__ w_off, const float* __restrict__ b_off,
        const float* __restrict__ w_attn, const float* __restrict__ b_attn,
        const float* __restrict__ w_out, const float* __restrict__ w1,
        const float* __restrict__ w2, const float* __restrict__ w_dw,
        unsigned short* __restrict__ qkvT, float* __restrict__ qkvB,
        unsigned short* __restrict__ woutT, unsigned short* __restrict__ w1T,
        unsigned short* __restrict__ w2T, float* __restrict__ wdwT) {
    const int blk = blockIdx.x;
    const int t = threadIdx.x;
    if (blk < NQKV) {                      // qkvT row n, K=256
        const int n = blk;
        float val = 0.0f;
        if (n < 256)       val = w_v[t * 256 + n];
        else if (n < 400)  val = w_off[t * 144 + (n - 256)];
        else if (n < 472)  val = w_attn[t * 72 + (n - 400)];
        qkvT[n * 256 + t] = f2bf(val);
        if (t == 0) {
            float bv = 0.0f;
            if (n < 256)      bv = b_v[n];
            else if (n < 400) bv = b_off[n - 256];
            else if (n < 472) bv = b_attn[n - 400];
            qkvB[n] = bv;
        }
    } else if (blk < NQKV + 256) {         // woutT row n, K=256
        const int n = blk - NQKV;
        woutT[n * 256 + t] = f2bf(w_out[t * 256 + n]);
    } else if (blk < NQKV + 256 + 1024) {  // w1T row n, K=256
        const int n = blk - (NQKV + 256);
        w1T[n * 256 + t] = f2bf(w1[t * 1024 + n]);
    } else if (blk < NQKV + 256 + 1024 + 256) { // w2T row n, K=1024
        const int n = blk - (NQKV + 256 + 1024);
        #pragma unroll
        for (int k = t; k < 1024; k += 256)
            w2T[n * 1024 + k] = f2bf(w2[k * 256 + n]);
    } else {                               // wdwT row j (9 rows)
        const int j = blk - (NQKV + 256 + 1024 + 256);
        #pragma unroll
        for (int c = t; c < HIDDEN; c += 256)
            wdwT[j * HIDDEN + c] = w_dw[c * 9 + j];
    }
}

// ---------------- bf16 MFMA GEMM: Out[M,N] = A[M,K] @ BT[N,K]^T + bias ----------------
// Tile 128 x BN, BK=64, 256 threads (4 waves, 2x2 wave grid), 16x16x32 bf16 MFMA.
// Grid: blockIdx.x = row panel (fastest) so the col-blocks of one row panel land on the
// SAME XCD (ids differ by Mrows/128=128, 128%8==0) -> A panel fetched by one L2 only.
// K-loop LDS: [rows][64] bf16, XOR swizzle byte^=((row&7)<<4) via pre-swizzled source.
// Epilogue: C-tile staged in (now dead) LDS, then streamed out with dwordx4 stores.
template<int BN, bool GELU, bool RESID, typename TO>
__global__ __launch_bounds__(256) void mfma_gemm(
        const unsigned short* __restrict__ A,   // [M,K] bf16
        const unsigned short* __restrict__ BT,  // [N,K] bf16
        const float* __restrict__ bias,         // [N]
        const float* __restrict__ resid,        // [M,N] f32 (if RESID)
        TO* __restrict__ Out,                   // [M,N]
        int N, int K) {
    constexpr int NFR = BN / 32;                // B fragments per wave (128->4, 64->2)
    // 32 KB serves both: K-loop staging (A 16K + B up to 16K) and epilogue C-tile
    // (128 rows x 256 B: bf16 BN=128 or f32 BN=64).
    __shared__ __align__(16) char lds[32768];
    unsigned short* As = (unsigned short*)lds;
    unsigned short* Bs = (unsigned short*)(lds + 16384);
    const int t = threadIdx.x;
    const int w = t >> 6;
    const int l = t & 63;
    const int row0 = blockIdx.x * 128;
    const int col0 = blockIdx.y * BN;
    const int wr = (w >> 1) * 64;               // wave row offset in tile
    const int wc = (w & 1) * (BN / 2);          // wave col offset in tile

    // staging geometry: chunk = 8 rows x 64 cols (1024 B); lane l -> row c*8+l/8,
    // 16B slot (l%8); source slot is XOR-swizzled so LDS holds swizzled layout.
    const int srow = l >> 3;
    const int selem = ((l & 7) ^ srow) * 8;     // element offset of this lane's 16B

    f32x4 acc[4][NFR] = {};

    for (int k0 = 0; k0 < K; k0 += 64) {
        #pragma unroll
        for (int i = 0; i < 4; ++i) {           // A tile: 16 chunks, 4 per wave
            const int c = w + i * 4;
            const int row = c * 8 + srow;
            gl2lds16(A + (size_t)(row0 + row) * K + k0 + selem, As + c * 512);
        }
        #pragma unroll
        for (int i = 0; i < NFR; ++i) {         // B tile: BN/8 chunks
            const int c = w + i * 4;
            const int row = c * 8 + srow;
            gl2lds16(BT + (size_t)(col0 + row) * K + k0 + selem, Bs + c * 512);
        }
        asm volatile("s_waitcnt vmcnt(0)" ::: "memory");
        __syncthreads();
        #pragma unroll
        for (int ks = 0; ks < 2; ++ks) {
            const int kb = ks * 64 + (l >> 4) * 16;   // byte offset within 128B row
            bf16x8 af[4], bfr[NFR];
            #pragma unroll
            for (int mi = 0; mi < 4; ++mi) {
                const int row = wr + mi * 16 + (l & 15);
                af[mi] = *(const bf16x8*)((const char*)As + row * 128 + (kb ^ ((row & 7) << 4)));
            }
            #pragma unroll
            for (int ni = 0; ni < NFR; ++ni) {
                const int row = wc + ni * 16 + (l & 15);
                bfr[ni] = *(const bf16x8*)((const char*)Bs + row * 128 + (kb ^ ((row & 7) << 4)));
            }
            #pragma unroll
            for (int mi = 0; mi < 4; ++mi)
                #pragma unroll
                for (int ni = 0; ni < NFR; ++ni)
                    acc[mi][ni] = __builtin_amdgcn_mfma_f32_16x16x32_bf16(
                        af[mi], bfr[ni], acc[mi][ni], 0, 0, 0);
        }
        __syncthreads();
    }

    // ---- epilogue phase 1: stage C-tile into LDS (256 B per row, row-XOR swizzle) ----
    // MFMA C/D layout: col=l&15, row=(l>>4)*4+reg (guide §3, m89-verified)
    const int lrow = (l >> 4) * 4;
    const int lcol = l & 15;
    #pragma unroll
    for (int ni = 0; ni < NFR; ++ni) {
        const int col = wc + ni * 16 + lcol;            // tile-relative col
        const float bb = bias[col0 + col];
        #pragma unroll
        for (int mi = 0; mi < 4; ++mi) {
            #pragma unroll
            for (int r = 0; r < 4; ++r) {
                const int row = wr + mi * 16 + lrow + r;
                float v = acc[mi][ni][r] + bb;
                if constexpr (GELU) v = gelu_exact(v);
                if constexpr (std::is_same<TO, unsigned short>::value) {
                    *(unsigned short*)(lds + row * 256 + ((col * 2) ^ ((row & 7) << 4))) = f2bf(v);
                } else {
                    *(float*)(lds + row * 256 + ((col * 4) ^ ((row & 7) << 4))) = v;
                }
            }
        }
    }
    __syncthreads();
    // ---- epilogue phase 2: wide coalesced write-back (8 x 16B per thread) ----
    const int rr = t >> 1;                    // tile row (128 rows, 2 threads each)
    const int hf = t & 1;                     // which 128-byte half of the row
    if constexpr (std::is_same<TO, unsigned short>::value) {
        unsigned short* obase = Out + (size_t)(row0 + rr) * N + col0;
        #pragma unroll
        for (int i = 0; i < 8; ++i) {
            const int bo = hf * 128 + i * 16;
            const int4 val = *(const int4*)(lds + rr * 256 + (bo ^ ((rr & 7) << 4)));
            *(int4*)(obase + bo / 2) = val;
        }
    } else {
        float* obase = (float*)Out + (size_t)(row0 + rr) * N + col0;
        const float* rbase = RESID ? (resid + (size_t)(row0 + rr) * N + col0) : nullptr;
        #pragma unroll
        for (int i = 0; i < 8; ++i) {
            const int bo = hf * 128 + i * 16;
            float4 val = *(const float4*)(lds + rr * 256 + (bo ^ ((rr & 7) << 4)));
            if constexpr (RESID) {
                const float4 rv = *(const float4*)(rbase + bo / 4);
                val.x += rv.x; val.y += rv.y; val.z += rv.z; val.w += rv.w;
            }
            *(float4*)(obase + bo / 4) = val;
        }
    }
}

// ---------------- Deformable sampling + softmax + aggregation (bf16 in/out) ----------------
// F = fused QKV buffer [M, 512]: cols 0-255 v, 256-399 offsets, 400-471 attn logits.
// 4 pixels per block (one wave each); within a pixel, lane tl: head = tl>>3, quad = tl&7
// owns 4 channels -> 8 B gathers (8 lanes x 8 B = one 64 B segment per head-corner).
__global__ __launch_bounds__(256) void sample_kernel(const unsigned short* __restrict__ F,
        const float* __restrict__ refp, unsigned short* __restrict__ agg) {
    constexpr int PPB = 4;                       // pixels per block
    const int m0 = blockIdx.x * PPB;             // 8192 % 4 == 0 -> same batch for all 4
    const int b = m0 / NPIX;
    const int pix0 = m0 - b * NPIX;
    const int t = threadIdx.x;
    __shared__ int4   s_idx[PPB][72];
    __shared__ float4 s_w[PPB][72];
    __shared__ float  s_lg[PPB][72];

    // phase 1: coords + bilinear corners/weights + logits (288 items on 256 threads)
    for (int idx = t; idx < PPB * 72; idx += 256) {
        const int p = idx / 72, hk = idx - p * 72;
        const int head = hk / 9, k = hk - head * 9;
        const int m = m0 + p, pix = pix0 + p;
        const size_t fb = (size_t)m * NQKV;
        const unsigned int ou = *(const unsigned int*)(F + fb + 256 + head * 18 + k * 2);
        const float ox = __uint_as_float(ou << 16);
        const float oy = __uint_as_float(ou & 0xffff0000u);
        const float2 rr = *(const float2*)(refp + ((size_t)pix * KPT + k) * 2);
        const float cx = (rr.x + ox + 1.0f) * 0.5f * (Wc - 1);
        const float cy = (rr.y + oy + 1.0f) * 0.5f * (Hc - 1);
        const float fx = floorf(cx), fy = floorf(cy);
        const float wx = cx - fx, wy = cy - fy;
        const int x0 = min(max((int)fx, 0), Wc - 1);
        const int x1 = min(max((int)fx + 1, 0), Wc - 1);
        const int y0 = min(max((int)fy, 0), Hc - 1);
        const int y1 = min(max((int)fy + 1, 0), Hc - 1);
        s_idx[p][hk] = make_int4(y0 * Wc + x0, y0 * Wc + x1, y1 * Wc + x0, y1 * Wc + x1);
        s_w[p][hk] = make_float4((1.0f - wy) * (1.0f - wx), (1.0f - wy) * wx,
                                 wy * (1.0f - wx), wy * wx);
        s_lg[p][hk] = bf2f(F[fb + 400 + hk]);
    }
    __syncthreads();
    // phase 2: softmax over k per (p, head); premultiply attn into corner weights
    for (int idx = t; idx < PPB * 72; idx += 256) {
        const int p = idx / 72, hk = idx - p * 72;
        const int h9 = (hk / 9) * 9;
        float mx = -1e30f;
        #pragma unroll
        for (int k = 0; k < 9; ++k) mx = fmaxf(mx, s_lg[p][h9 + k]);
        float sm = 0.0f;
        #pragma unroll
        for (int k = 0; k < 9; ++k) sm += __expf(s_lg[p][h9 + k] - mx);
        const float a = __expf(s_lg[p][hk] - mx) / sm;
        float4 w = s_w[p][hk];
        w.x *= a; w.y *= a; w.z *= a; w.w *= a;
        s_w[p][hk] = w;
    }
    __syncthreads();
    // phase 3: gather-accumulate, 4 channels per lane
    const int p = t >> 6, tl = t & 63;
    const int head = tl >> 3, dq = tl & 7;
    const unsigned short* vb = F + (size_t)b * NPIX * NQKV + head * HD + dq * 4;
    float a0 = 0.f, a1 = 0.f, a2 = 0.f, a3 = 0.f;
    #pragma unroll
    for (int k = 0; k < 9; ++k) {
        const int hk = head * 9 + k;
        const int4   ix = s_idx[p][hk];
        const float4 ww = s_w[p][hk];
        {
            const uint2 u = *(const uint2*)(vb + (size_t)ix.x * NQKV);
            a0 += __uint_as_float(u.x << 16) * ww.x;
            a1 += __uint_as_float(u.x & 0xffff0000u) * ww.x;
            a2 += __uint_as_float(u.y << 16) * ww.x;
            a3 += __uint_as_float(u.y & 0xffff0000u) * ww.x;
        }
        {
            const uint2 u = *(const uint2*)(vb + (size_t)ix.y * NQKV);
            a0 += __uint_as_float(u.x << 16) * ww.y;
            a1 += __uint_as_float(u.x & 0xffff0000u) * ww.y;
            a2 += __uint_as_float(u.y << 16) * ww.y;
            a3 += __uint_as_float(u.y & 0xffff0000u) * ww.y;
        }
        {
            const uint2 u = *(const uint2*)(vb + (size_t)ix.z * NQKV);
            a0 += __uint_as_float(u.x << 16) * ww.z;
            a1 += __uint_as_float(u.x & 0xffff0000u) * ww.z;
            a2 += __uint_as_float(u.y << 16) * ww.z;
            a3 += __uint_as_float(u.y & 0xffff0000u) * ww.z;
        }
        {
            const uint2 u = *(const uint2*)(vb + (size_t)ix.w * NQKV);
            a0 += __uint_as_float(u.x << 16) * ww.w;
            a1 += __uint_as_float(u.x & 0xffff0000u) * ww.w;
            a2 += __uint_as_float(u.y << 16) * ww.w;
            a3 += __uint_as_float(u.y & 0xffff0000u) * ww.w;
        }
    }
    ushort4 o;
    o.x = f2bf(a0); o.y = f2bf(a1); o.z = f2bf(a2); o.w = f2bf(a3);
    *reinterpret_cast<ushort4*>(agg + (size_t)(m0 + p) * Cc + tl * 4) = o;
}

// ---------------- Depthwise 3x3 conv (circular W, zero H) + GELU, bf16 in/out ----------------
// Quad-of-pixels per block: each block computes 4 consecutive x positions for all 1024
// channels; thread t owns channels [4t,4t+4) for all 4 outputs. Loads 3 rows x 6 cols
// (18 independent ushort4 per thread) -> 2x less L2 traffic + 4x ILP vs 1-pixel blocks.
__global__ __launch_bounds__(256) void dwconv_kernel(const unsigned short* __restrict__ h,
        const float* __restrict__ wdwT, const float* __restrict__ bdw,
        unsigned short* __restrict__ h2) {
    constexpr int NQ = 4;                     // x-positions per block
    constexpr int nblk = Mrows / NQ;          // 4096
    const int bid = blockIdx.x;
    const int qi = (bid & 7) * (nblk / 8) + (bid >> 3);   // XCD-chunked swizzle (4096 % 8 == 0)
    const int m0 = qi * NQ;                   // quad never crosses a row (Wc % NQ == 0)
    const int b = m0 / NPIX;
    const int pix0 = m0 - b * NPIX;
    const int y = pix0 / Wc, x0 = pix0 - y * Wc;
    const int t = threadIdx.x;
    const int c0 = t * 4;

    float wreg[9][4];
    #pragma unroll
    for (int j = 0; j < 9; ++j) {
        const float4 wv = *reinterpret_cast<const float4*>(wdwT + j * HIDDEN + c0);
        wreg[j][0] = wv.x; wreg[j][1] = wv.y; wreg[j][2] = wv.z; wreg[j][3] = wv.w;
    }

    float acc[NQ][4] = {};
    #pragma unroll
    for (int dy = -1; dy <= 1; ++dy) {
        const int yy = y + dy;
        if (yy < 0 || yy >= Hc) continue;     // zero pad along height (block-uniform branch)
        const size_t rowbase = ((size_t)b * NPIX + (size_t)yy * Wc) * HIDDEN + c0;
        #pragma unroll
        for (int j = 0; j < NQ + 2; ++j) {    // columns x0-1 .. x0+NQ (circular)
            const int xx = (x0 + j - 1 + Wc) & (Wc - 1);
            const ushort4 hv = *reinterpret_cast<const ushort4*>(h + rowbase + (size_t)xx * HIDDEN);
            const float f0 = bf2f(hv.x), f1 = bf2f(hv.y), f2 = bf2f(hv.z), f3 = bf2f(hv.w);
            #pragma unroll
            for (int q = 0; q < NQ; ++q) {
                if (q >= j - 2 && q <= j) {   // folds to constants after unroll
                    const int wj = (dy + 1) * 3 + (j - q);
                    acc[q][0] += f0 * wreg[wj][0];
                    acc[q][1] += f1 * wreg[wj][1];
                    acc[q][2] += f2 * wreg[wj][2];
                    acc[q][3] += f3 * wreg[wj][3];
                }
            }
        }
    }
    const float4 bb = *reinterpret_cast<const float4*>(bdw + c0);
    #pragma unroll
    for (int q = 0; q < NQ; ++q) {
        ushort4 o;
        o.x = f2bf(gelu_exact(acc[q][0] + bb.x));
        o.y = f2bf(gelu_exact(acc[q][1] + bb.y));
        o.z = f2bf(gelu_exact(acc[q][2] + bb.z));
        o.w = f2bf(gelu_exact(acc[q][3] + bb.w));
        *reinterpret_cast<ushort4*>(h2 + (size_t)(m0 + q) * HIDDEN + c0) = o;
    }
}

extern "C" void kernel_launch(void* const* d_in, const int* in_sizes, int n_in,
                              void* d_out, int out_size, void* d_ws, size_t ws_size,
                              hipStream_t stream) {
    const float* x      = (const float*)d_in[0];
    const float* refp   = (const float*)d_in[1];
    const float* ln1_g  = (const float*)d_in[2];
    const float* ln1_b  = (const float*)d_in[3];
    const float* w_v    = (const float*)d_in[4];
    const float* b_v    = (const float*)d_in[5];
    const float* w_off  = (const float*)d_in[6];
    const float* b_off  = (const float*)d_in[7];
    const float* w_attn = (const float*)d_in[8];
    const float* b_attn = (const float*)d_in[9];
    const float* w_out  = (const float*)d_in[10];
    const float* b_out  = (const float*)d_in[11];
    const float* ln2_g  = (const float*)d_in[12];
    const float* ln2_b  = (const float*)d_in[13];
    const float* w1     = (const float*)d_in[14];
    const float* b1     = (const float*)d_in[15];
    const float* w_dw   = (const float*)d_in[16];
    const float* b_dw   = (const float*)d_in[17];
    const float* w2     = (const float*)d_in[18];
    const float* b2     = (const float*)d_in[19];
    float* out = (float*)d_out;

    // Workspace layout (bytes); lifetimes make the overlaps safe:
    //  [0,  8M): xn -> agg -> y          (bf16 [M,256], sequential reuse)
    //  [8, 24M): F fused qkv (bf16 [M,512]) — dead after sample_kernel
    //  [8, 40M): h (bf16 [M,1024])       — written after F is dead
    //  [40,72M): h2 (bf16 [M,1024])
    //  [72M,..): transposed bf16 weights + wdwT + fused qkv bias
    char* wsb = (char*)d_ws;
    unsigned short* xnR = (unsigned short*)(wsb);
    unsigned short* F   = (unsigned short*)(wsb + (8ull  << 20));
    unsigned short* h   = (unsigned short*)(wsb + (8ull  << 20));
    unsigned short* h2  = (unsigned short*)(wsb + (40ull << 20));
    size_t woff = 72ull << 20;
    unsigned short* qkvT = (unsigned short*)(wsb + woff); woff += (size_t)NQKV * 256 * 2;
    unsigned short* woutT= (unsigned short*)(wsb + woff); woff += 256 * 256 * 2;
    unsigned short* w1T  = (unsigned short*)(wsb + woff); woff += 1024 * 256 * 2;
    unsigned short* w2T  = (unsigned short*)(wsb + woff); woff += 256 * 1024 * 2;
    float*          wdwT = (float*)(wsb + woff);          woff += 9 * 1024 * 4;
    float*          qkvB = (float*)(wsb + woff);

    // 0. weight transpose/convert (independent of activations)
    prep_weights<<<NQKV + 256 + 1024 + 256 + 9, 256, 0, stream>>>(
        w_v, b_v, w_off, b_off, w_attn, b_attn, w_out, w1, w2, w_dw,
        qkvT, qkvB, woutT, w1T, w2T, wdwT);
    // 1. LN1 -> xn (bf16)
    ln_kernel<unsigned short><<<Mrows, 256, 0, stream>>>(x, ln1_g, ln1_b, xnR);
    // 2. fused QKV GEMM: F = xn @ [w_v|w_off|w_attn] + bias  (bf16 out)
    mfma_gemm<128, false, false, unsigned short><<<dim3(Mrows / 128, NQKV / 128), 256, 0, stream>>>(
        xnR, qkvT, qkvB, nullptr, F, NQKV, 256);
    // 3. deformable sampling + softmax + aggregation -> agg (reuses xn region)
    sample_kernel<<<Mrows / 4, 256, 0, stream>>>(F, refp, xnR);
    // 4. x2 = x + agg @ w_out + b_out -> d_out (f32)
    mfma_gemm<64, false, true, float><<<dim3(Mrows / 128, 256 / 64), 256, 0, stream>>>(
        xnR, woutT, b_out, x, out, 256, 256);
    // 5. LN2 -> y (bf16, reuses xn region)
    ln_kernel<unsigned short><<<Mrows, 256, 0, stream>>>(out, ln2_g, ln2_b, xnR);
    // 6. h = gelu(y @ w1 + b1) (bf16)
    mfma_gemm<128, true, false, unsigned short><<<dim3(Mrows / 128, 1024 / 128), 256, 0, stream>>>(
        xnR, w1T, b1, nullptr, h, 1024, 256);
    // 7. depthwise conv + gelu -> h2 (bf16)
    dwconv_kernel<<<Mrows / 4, 256, 0, stream>>>(h, wdwT, b_dw, h2);
    // 8. out = x2 + h2 @ w2 + b2 (f32, in-place residual)
    mfma_gemm<64, false, true, float><<<dim3(Mrows / 128, 256 / 64), 256, 0, stream>>>(
        h2, w2T, b2, out, out, 256, 1024);
}

// Round 7
// 170.001 us; speedup vs baseline: 1.0460x; 1.0160x over previous
//
#include <hip/hip_runtime.h>
#include <hip/hip_bf16.h>
#include <type_traits>

// Problem constants
constexpr int Bc = 2, Hc = 64, Wc = 128, Cc = 256;
constexpr int HEADS = 8, KPT = 9, HIDDEN = 1024;
constexpr int HD = Cc / HEADS;           // 32
constexpr int NPIX = Hc * Wc;            // 8192
constexpr int Mrows = Bc * NPIX;         // 16384
constexpr int NQKV = 512;                // 256 (v) + 144 (off) + 72 (attn) padded to 512

typedef __attribute__((ext_vector_type(4))) float f32x4;
typedef __attribute__((ext_vector_type(8))) short bf16x8;

__device__ __forceinline__ float bf2f(unsigned short u) {
    union { unsigned int i; float f; } c; c.i = ((unsigned int)u) << 16; return c.f;
}
__device__ __forceinline__ unsigned short f2bf(float f) {
    __hip_bfloat16 h = __float2bfloat16(f);
    return *reinterpret_cast<unsigned short*>(&h);
}
__device__ __forceinline__ float gelu_exact(float x) {
    return 0.5f * x * (1.0f + erff(x * 0.70710678118654752f));
}
__device__ __forceinline__ void gl2lds16(const void* g, void* l) {
    __builtin_amdgcn_global_load_lds(
        (const __attribute__((address_space(1))) unsigned int*)g,
        (__attribute__((address_space(3))) unsigned int*)l, 16, 0, 0);
}

// ---------------- LayerNorm over C=256, one row per 256-thread block ----------------
template<typename TO>
__global__ __launch_bounds__(256) void ln_kernel(const float* __restrict__ in,
        const float* __restrict__ g, const float* __restrict__ b,
        TO* __restrict__ out) {
    const int r = blockIdx.x;
    const int t = threadIdx.x;
    const size_t base = (size_t)r * Cc;
    float val = in[base + t];
    float s = val, s2 = val * val;
    #pragma unroll
    for (int o = 32; o > 0; o >>= 1) { s += __shfl_down(s, o); s2 += __shfl_down(s2, o); }
    __shared__ float ps[4], ps2[4];
    if ((t & 63) == 0) { ps[t >> 6] = s; ps2[t >> 6] = s2; }
    __syncthreads();
    const float ts  = ps[0] + ps[1] + ps[2] + ps[3];
    const float ts2 = ps2[0] + ps2[1] + ps2[2] + ps2[3];
    const float mean = ts * (1.0f / Cc);
    const float var  = ts2 * (1.0f / Cc) - mean * mean;
    const float rstd = rsqrtf(var + 1e-5f);
    const float v = (val - mean) * rstd * g[t] + b[t];
    if constexpr (std::is_same<TO, float>::value) out[base + t] = v;
    else out[base + t] = f2bf(v);
}

// ---------------- Weight prep: f32 [K,N] -> bf16 [N,K] (transposed), QKV fused+padded ----
// Also transposes depthwise weights [1024][9] -> [9][1024] f32 for coalesced loads.
__global__ __launch_bounds__(256) void prep_weights(
        const float* __restrict__ w_v, const float* __restrict__ b_v,
        const float* __restrict__ w_off, const float* __restrict__ b_off,
        const float* __restrict__ w_attn, const float* __restrict__ b_attn,
        const float* __restrict__ w_out, const float* __restrict__ w1,
        const float* __restrict__ w2, const float* __restrict__ w_dw,
        unsigned short* __restrict__ qkvT, float* __restrict__ qkvB,
        unsigned short* __restrict__ woutT, unsigned short* __restrict__ w1T,
        unsigned short* __restrict__ w2T, float* __restrict__ wdwT) {
    const int blk = blockIdx.x;
    const int t = threadIdx.x;
    if (blk < NQKV) {                      // qkvT row n, K=256
        const int n = blk;
        float val = 0.0f;
        if (n < 256)       val = w_v[t * 256 + n];
        else if (n < 400)  val = w_off[t * 144 + (n - 256)];
        else if (n < 472)  val = w_attn[t * 72 + (n - 400)];
        qkvT[n * 256 + t] = f2bf(val);
        if (t == 0) {
            float bv = 0.0f;
            if (n < 256)      bv = b_v[n];
            else if (n < 400) bv = b_off[n - 256];
            else if (n < 472) bv = b_attn[n - 400];
            qkvB[n] = bv;
        }
    } else if (blk < NQKV + 256) {         // woutT row n, K=256
        const int n = blk - NQKV;
        woutT[n * 256 + t] = f2bf(w_out[t * 256 + n]);
    } else if (blk < NQKV + 256 + 1024) {  // w1T row n, K=256
        const int n = blk - (NQKV + 256);
        w1T[n * 256 + t] = f2bf(w1[t * 1024 + n]);
    } else if (blk < NQKV + 256 + 1024 + 256) { // w2T row n, K=1024
        const int n = blk - (NQKV + 256 + 1024);
        #pragma unroll
        for (int k = t; k < 1024; k += 256)
            w2T[n * 1024 + k] = f2bf(w2[k * 256 + n]);
    } else {                               // wdwT row j (9 rows)
        const int j = blk - (NQKV + 256 + 1024 + 256);
        #pragma unroll
        for (int c = t; c < HIDDEN; c += 256)
            wdwT[j * HIDDEN + c] = w_dw[c * 9 + j];
    }
}

// ---------------- bf16 MFMA GEMM: Out[M,N] = A[M,K] @ BT[N,K]^T + bias ----------------
// Tile 128 x BN, BK=64, 256 threads (4 waves, 2x2 wave grid), 16x16x32 bf16 MFMA.
// Grid: blockIdx.x = row panel (fastest) so the col-blocks of one row panel land on the
// SAME XCD (ids differ by Mrows/128=128, 128%8==0) -> A panel fetched by one L2 only.
// K-loop: T3 minimum 2-phase double-buffer (guide §5.5): issue next tile's
// global_load_lds BEFORE computing current tile, raw s_barrier + manual vmcnt(0)
// at step end so the DMA latency hides under MFMA (no __syncthreads vmcnt-drain).
// LDS per K-tile: [rows][64] bf16, XOR swizzle byte^=((row&7)<<4) via pre-swizzled src.
// Epilogue: C-tile staged in (now dead) LDS, then streamed out with dwordx4 stores.
template<int BN, bool GELU, bool RESID, typename TO>
__global__ __launch_bounds__(256) void mfma_gemm(
        const unsigned short* __restrict__ A,   // [M,K] bf16
        const unsigned short* __restrict__ BT,  // [N,K] bf16
        const float* __restrict__ bias,         // [N]
        const float* __restrict__ resid,        // [M,N] f32 (if RESID)
        TO* __restrict__ Out,                   // [M,N]
        int N, int K) {
    constexpr int NFR = BN / 32;                // B fragments per wave (128->4, 64->2)
    constexpr int BUFB = 16384 + BN * 128;      // A tile 16 KB + B tile (BN*64*2 B)
    // double buffer (BN=128: 64 KB, BN=64: 48 KB); epilogue C-tile (32 KB) reuses it.
    __shared__ __align__(16) char lds[2 * BUFB];
    const int t = threadIdx.x;
    const int w = t >> 6;
    const int l = t & 63;
    const int row0 = blockIdx.x * 128;
    const int col0 = blockIdx.y * BN;
    const int wr = (w >> 1) * 64;               // wave row offset in tile
    const int wc = (w & 1) * (BN / 2);          // wave col offset in tile

    // staging geometry: chunk = 8 rows x 64 cols (1024 B); lane l -> row c*8+l/8,
    // 16B slot (l%8); source slot is XOR-swizzled so LDS holds swizzled layout.
    const int srow = l >> 3;
    const int selem = ((l & 7) ^ srow) * 8;     // element offset of this lane's 16B

    auto stage = [&](char* buf, int k0) {
        unsigned short* As_ = (unsigned short*)buf;
        unsigned short* Bs_ = (unsigned short*)(buf + 16384);
        #pragma unroll
        for (int i = 0; i < 4; ++i) {           // A tile: 16 chunks, 4 per wave
            const int c = w + i * 4;
            const int row = c * 8 + srow;
            gl2lds16(A + (size_t)(row0 + row) * K + k0 + selem, As_ + c * 512);
        }
        #pragma unroll
        for (int i = 0; i < NFR; ++i) {         // B tile: BN/8 chunks
            const int c = w + i * 4;
            const int row = c * 8 + srow;
            gl2lds16(BT + (size_t)(col0 + row) * K + k0 + selem, Bs_ + c * 512);
        }
    };

    f32x4 acc[4][NFR] = {};
    const int nt = K / 64;

    // prologue: stage tile 0, wait, barrier
    stage(lds, 0);
    asm volatile("s_waitcnt vmcnt(0)" ::: "memory");
    __builtin_amdgcn_s_barrier();

    int cur = 0;
    for (int tt = 0; tt < nt; ++tt) {
        if (tt + 1 < nt) stage(lds + (size_t)(cur ^ 1) * BUFB, (tt + 1) * 64);
        const char* Ab = lds + (size_t)cur * BUFB;
        const char* Bb = Ab + 16384;
        #pragma unroll
        for (int ks = 0; ks < 2; ++ks) {
            const int kb = ks * 64 + (l >> 4) * 16;   // byte offset within 128B row
            bf16x8 af[4], bfr[NFR];
            #pragma unroll
            for (int mi = 0; mi < 4; ++mi) {
                const int row = wr + mi * 16 + (l & 15);
                af[mi] = *(const bf16x8*)(Ab + row * 128 + (kb ^ ((row & 7) << 4)));
            }
            #pragma unroll
            for (int ni = 0; ni < NFR; ++ni) {
                const int row = wc + ni * 16 + (l & 15);
                bfr[ni] = *(const bf16x8*)(Bb + row * 128 + (kb ^ ((row & 7) << 4)));
            }
            #pragma unroll
            for (int mi = 0; mi < 4; ++mi)
                #pragma unroll
                for (int ni = 0; ni < NFR; ++ni)
                    acc[mi][ni] = __builtin_amdgcn_mfma_f32_16x16x32_bf16(
                        af[mi], bfr[ni], acc[mi][ni], 0, 0, 0);
        }
        // next tile's DMA (hidden under the compute above) must be complete, and all
        // waves must be done reading buf[cur], before anyone proceeds / re-stages.
        asm volatile("s_waitcnt vmcnt(0) lgkmcnt(0)" ::: "memory");
        __builtin_amdgcn_s_barrier();
        cur ^= 1;
    }

    // ---- epilogue phase 1: stage C-tile into LDS (256 B per row, row-XOR swizzle) ----
    // MFMA C/D layout: col=l&15, row=(l>>4)*4+reg (guide §3, m89-verified)
    const int lrow = (l >> 4) * 4;
    const int lcol = l & 15;
    #pragma unroll
    for (int ni = 0; ni < NFR; ++ni) {
        const int col = wc + ni * 16 + lcol;            // tile-relative col
        const float bb = bias[col0 + col];
        #pragma unroll
        for (int mi = 0; mi < 4; ++mi) {
            #pragma unroll
            for (int r = 0; r < 4; ++r) {
                const int row = wr + mi * 16 + lrow + r;
                float v = acc[mi][ni][r] + bb;
                if constexpr (GELU) v = gelu_exact(v);
                if constexpr (std::is_same<TO, unsigned short>::value) {
                    *(unsigned short*)(lds + row * 256 + ((col * 2) ^ ((row & 7) << 4))) = f2bf(v);
                } else {
                    *(float*)(lds + row * 256 + ((col * 4) ^ ((row & 7) << 4))) = v;
                }
            }
        }
    }
    __syncthreads();
    // ---- epilogue phase 2: wide coalesced write-back (8 x 16B per thread) ----
    const int rr = t >> 1;                    // tile row (128 rows, 2 threads each)
    const int hf = t & 1;                     // which 128-byte half of the row
    if constexpr (std::is_same<TO, unsigned short>::value) {
        unsigned short* obase = Out + (size_t)(row0 + rr) * N + col0;
        #pragma unroll
        for (int i = 0; i < 8; ++i) {
            const int bo = hf * 128 + i * 16;
            const int4 val = *(const int4*)(lds + rr * 256 + (bo ^ ((rr & 7) << 4)));
            *(int4*)(obase + bo / 2) = val;
        }
    } else {
        float* obase = (float*)Out + (size_t)(row0 + rr) * N + col0;
        const float* rbase = RESID ? (resid + (size_t)(row0 + rr) * N + col0) : nullptr;
        #pragma unroll
        for (int i = 0; i < 8; ++i) {
            const int bo = hf * 128 + i * 16;
            float4 val = *(const float4*)(lds + rr * 256 + (bo ^ ((rr & 7) << 4)));
            if constexpr (RESID) {
                const float4 rv = *(const float4*)(rbase + bo / 4);
                val.x += rv.x; val.y += rv.y; val.z += rv.z; val.w += rv.w;
            }
            *(float4*)(obase + bo / 4) = val;
        }
    }
}

// ---------------- Deformable sampling + softmax + aggregation (bf16 in/out) ----------------
// F = fused QKV buffer [M, 512]: cols 0-255 v, 256-399 offsets, 400-471 attn logits.
// 4 pixels per block (one wave each); within a pixel, lane tl: head = tl>>3, quad = tl&7
// owns 4 channels -> 8 B gathers (8 lanes x 8 B = one 64 B segment per head-corner).
__global__ __launch_bounds__(256) void sample_kernel(const unsigned short* __restrict__ F,
        const float* __restrict__ refp, unsigned short* __restrict__ agg) {
    constexpr int PPB = 4;                       // pixels per block
    const int m0 = blockIdx.x * PPB;             // 8192 % 4 == 0 -> same batch for all 4
    const int b = m0 / NPIX;
    const int pix0 = m0 - b * NPIX;
    const int t = threadIdx.x;
    __shared__ int4   s_idx[PPB][72];
    __shared__ float4 s_w[PPB][72];
    __shared__ float  s_lg[PPB][72];

    // phase 1: coords + bilinear corners/weights + logits (288 items on 256 threads)
    for (int idx = t; idx < PPB * 72; idx += 256) {
        const int p = idx / 72, hk = idx - p * 72;
        const int head = hk / 9, k = hk - head * 9;
        const int m = m0 + p, pix = pix0 + p;
        const size_t fb = (size_t)m * NQKV;
        const unsigned int ou = *(const unsigned int*)(F + fb + 256 + head * 18 + k * 2);
        const float ox = __uint_as_float(ou << 16);
        const float oy = __uint_as_float(ou & 0xffff0000u);
        const float2 rr = *(const float2*)(refp + ((size_t)pix * KPT + k) * 2);
        const float cx = (rr.x + ox + 1.0f) * 0.5f * (Wc - 1);
        const float cy = (rr.y + oy + 1.0f) * 0.5f * (Hc - 1);
        const float fx = floorf(cx), fy = floorf(cy);
        const float wx = cx - fx, wy = cy - fy;
        const int x0 = min(max((int)fx, 0), Wc - 1);
        const int x1 = min(max((int)fx + 1, 0), Wc - 1);
        const int y0 = min(max((int)fy, 0), Hc - 1);
        const int y1 = min(max((int)fy + 1, 0), Hc - 1);
        s_idx[p][hk] = make_int4(y0 * Wc + x0, y0 * Wc + x1, y1 * Wc + x0, y1 * Wc + x1);
        s_w[p][hk] = make_float4((1.0f - wy) * (1.0f - wx), (1.0f - wy) * wx,
                                 wy * (1.0f - wx), wy * wx);
        s_lg[p][hk] = bf2f(F[fb + 400 + hk]);
    }
    __syncthreads();
    // phase 2: softmax over k per (p, head); premultiply attn into corner weights
    for (int idx = t; idx < PPB * 72; idx += 256) {
        const int p = idx / 72, hk = idx - p * 72;
        const int h9 = (hk / 9) * 9;
        float mx = -1e30f;
        #pragma unroll
        for (int k = 0; k < 9; ++k) mx = fmaxf(mx, s_lg[p][h9 + k]);
        float sm = 0.0f;
        #pragma unroll
        for (int k = 0; k < 9; ++k) sm += __expf(s_lg[p][h9 + k] - mx);
        const float a = __expf(s_lg[p][hk] - mx) / sm;
        float4 w = s_w[p][hk];
        w.x *= a; w.y *= a; w.z *= a; w.w *= a;
        s_w[p][hk] = w;
    }
    __syncthreads();
    // phase 3: gather-accumulate, 4 channels per lane
    const int p = t >> 6, tl = t & 63;
    const int head = tl >> 3, dq = tl & 7;
    const unsigned short* vb = F + (size_t)b * NPIX * NQKV + head * HD + dq * 4;
    float a0 = 0.f, a1 = 0.f, a2 = 0.f, a3 = 0.f;
    #pragma unroll
    for (int k = 0; k < 9; ++k) {
        const int hk = head * 9 + k;
        const int4   ix = s_idx[p][hk];
        const float4 ww = s_w[p][hk];
        {
            const uint2 u = *(const uint2*)(vb + (size_t)ix.x * NQKV);
            a0 += __uint_as_float(u.x << 16) * ww.x;
            a1 += __uint_as_float(u.x & 0xffff0000u) * ww.x;
            a2 += __uint_as_float(u.y << 16) * ww.x;
            a3 += __uint_as_float(u.y & 0xffff0000u) * ww.x;
        }
        {
            const uint2 u = *(const uint2*)(vb + (size_t)ix.y * NQKV);
            a0 += __uint_as_float(u.x << 16) * ww.y;
            a1 += __uint_as_float(u.x & 0xffff0000u) * ww.y;
            a2 += __uint_as_float(u.y << 16) * ww.y;
            a3 += __uint_as_float(u.y & 0xffff0000u) * ww.y;
        }
        {
            const uint2 u = *(const uint2*)(vb + (size_t)ix.z * NQKV);
            a0 += __uint_as_float(u.x << 16) * ww.z;
            a1 += __uint_as_float(u.x & 0xffff0000u) * ww.z;
            a2 += __uint_as_float(u.y << 16) * ww.z;
            a3 += __uint_as_float(u.y & 0xffff0000u) * ww.z;
        }
        {
            const uint2 u = *(const uint2*)(vb + (size_t)ix.w * NQKV);
            a0 += __uint_as_float(u.x << 16) * ww.w;
            a1 += __uint_as_float(u.x & 0xffff0000u) * ww.w;
            a2 += __uint_as_float(u.y << 16) * ww.w;
            a3 += __uint_as_float(u.y & 0xffff0000u) * ww.w;
        }
    }
    ushort4 o;
    o.x = f2bf(a0); o.y = f2bf(a1); o.z = f2bf(a2); o.w = f2bf(a3);
    *reinterpret_cast<ushort4*>(agg + (size_t)(m0 + p) * Cc + tl * 4) = o;
}

// ---------------- Depthwise 3x3 conv (circular W, zero H) + GELU, bf16 in/out ----------------
// Quad-of-pixels per block: each block computes 4 consecutive x positions for all 1024
// channels; thread t owns channels [4t,4t+4) for all 4 outputs. Loads 3 rows x 6 cols
// (18 independent ushort4 per thread) -> 2x less L2 traffic + 4x ILP vs 1-pixel blocks.
__global__ __launch_bounds__(256) void dwconv_kernel(const unsigned short* __restrict__ h,
        const float* __restrict__ wdwT, const float* __restrict__ bdw,
        unsigned short* __restrict__ h2) {
    constexpr int NQ = 4;                     // x-positions per block
    constexpr int nblk = Mrows / NQ;          // 4096
    const int bid = blockIdx.x;
    const int qi = (bid & 7) * (nblk / 8) + (bid >> 3);   // XCD-chunked swizzle (4096 % 8 == 0)
    const int m0 = qi * NQ;                   // quad never crosses a row (Wc % NQ == 0)
    const int b = m0 / NPIX;
    const int pix0 = m0 - b * NPIX;
    const int y = pix0 / Wc, x0 = pix0 - y * Wc;
    const int t = threadIdx.x;
    const int c0 = t * 4;

    float wreg[9][4];
    #pragma unroll
    for (int j = 0; j < 9; ++j) {
        const float4 wv = *reinterpret_cast<const float4*>(wdwT + j * HIDDEN + c0);
        wreg[j][0] = wv.x; wreg[j][1] = wv.y; wreg[j][2] = wv.z; wreg[j][3] = wv.w;
    }

    float acc[NQ][4] = {};
    #pragma unroll
    for (int dy = -1; dy <= 1; ++dy) {
        const int yy = y + dy;
        if (yy < 0 || yy >= Hc) continue;     // zero pad along height (block-uniform branch)
        const size_t rowbase = ((size_t)b * NPIX + (size_t)yy * Wc) * HIDDEN + c0;
        #pragma unroll
        for (int j = 0; j < NQ + 2; ++j) {    // columns x0-1 .. x0+NQ (circular)
            const int xx = (x0 + j - 1 + Wc) & (Wc - 1);
            const ushort4 hv = *reinterpret_cast<const ushort4*>(h + rowbase + (size_t)xx * HIDDEN);
            const float f0 = bf2f(hv.x), f1 = bf2f(hv.y), f2 = bf2f(hv.z), f3 = bf2f(hv.w);
            #pragma unroll
            for (int q = 0; q < NQ; ++q) {
                if (q >= j - 2 && q <= j) {   // folds to constants after unroll
                    const int wj = (dy + 1) * 3 + (j - q);
                    acc[q][0] += f0 * wreg[wj][0];
                    acc[q][1] += f1 * wreg[wj][1];
                    acc[q][2] += f2 * wreg[wj][2];
                    acc[q][3] += f3 * wreg[wj][3];
                }
            }
        }
    }
    const float4 bb = *reinterpret_cast<const float4*>(bdw + c0);
    #pragma unroll
    for (int q = 0; q < NQ; ++q) {
        ushort4 o;
        o.x = f2bf(gelu_exact(acc[q][0] + bb.x));
        o.y = f2bf(gelu_exact(acc[q][1] + bb.y));
        o.z = f2bf(gelu_exact(acc[q][2] + bb.z));
        o.w = f2bf(gelu_exact(acc[q][3] + bb.w));
        *reinterpret_cast<ushort4*>(h2 + (size_t)(m0 + q) * HIDDEN + c0) = o;
    }
}

extern "C" void kernel_launch(void* const* d_in, const int* in_sizes, int n_in,
                              void* d_out, int out_size, void* d_ws, size_t ws_size,
                              hipStream_t stream) {
    const float* x      = (const float*)d_in[0];
    const float* refp   = (const float*)d_in[1];
    const float* ln1_g  = (const float*)d_in[2];
    const float* ln1_b  = (const float*)d_in[3];
    const float* w_v    = (const float*)d_in[4];
    const float* b_v    = (const float*)d_in[5];
    const float* w_off  = (const float*)d_in[6];
    const float* b_off  = (const float*)d_in[7];
    const float* w_attn = (const float*)d_in[8];
    const float* b_attn = (const float*)d_in[9];
    const float* w_out  = (const float*)d_in[10];
    const float* b_out  = (const float*)d_in[11];
    const float* ln2_g  = (const float*)d_in[12];
    const float* ln2_b  = (const float*)d_in[13];
    const float* w1     = (const float*)d_in[14];
    const float* b1     = (const float*)d_in[15];
    const float* w_dw   = (const float*)d_in[16];
    const float* b_dw   = (const float*)d_in[17];
    const float* w2     = (const float*)d_in[18];
    const float* b2     = (const float*)d_in[19];
    float* out = (float*)d_out;

    // Workspace layout (bytes); lifetimes make the overlaps safe:
    //  [0,  8M): xn -> agg -> y          (bf16 [M,256], sequential reuse)
    //  [8, 24M): F fused qkv (bf16 [M,512]) — dead after sample_kernel
    //  [8, 40M): h (bf16 [M,1024])       — written after F is dead
    //  [40,72M): h2 (bf16 [M,1024])
    //  [72M,..): transposed bf16 weights + wdwT + fused qkv bias
    char* wsb = (char*)d_ws;
    unsigned short* xnR = (unsigned short*)(wsb);
    unsigned short* F   = (unsigned short*)(wsb + (8ull  << 20));
    unsigned short* h   = (unsigned short*)(wsb + (8ull  << 20));
    unsigned short* h2  = (unsigned short*)(wsb + (40ull << 20));
    size_t woff = 72ull << 20;
    unsigned short* qkvT = (unsigned short*)(wsb + woff); woff += (size_t)NQKV * 256 * 2;
    unsigned short* woutT= (unsigned short*)(wsb + woff); woff += 256 * 256 * 2;
    unsigned short* w1T  = (unsigned short*)(wsb + woff); woff += 1024 * 256 * 2;
    unsigned short* w2T  = (unsigned short*)(wsb + woff); woff += 256 * 1024 * 2;
    float*          wdwT = (float*)(wsb + woff);          woff += 9 * 1024 * 4;
    float*          qkvB = (float*)(wsb + woff);

    // 0. weight transpose/convert (independent of activations)
    prep_weights<<<NQKV + 256 + 1024 + 256 + 9, 256, 0, stream>>>(
        w_v, b_v, w_off, b_off, w_attn, b_attn, w_out, w1, w2, w_dw,
        qkvT, qkvB, woutT, w1T, w2T, wdwT);
    // 1. LN1 -> xn (bf16)
    ln_kernel<unsigned short><<<Mrows, 256, 0, stream>>>(x, ln1_g, ln1_b, xnR);
    // 2. fused QKV GEMM: F = xn @ [w_v|w_off|w_attn] + bias  (bf16 out)
    mfma_gemm<128, false, false, unsigned short><<<dim3(Mrows / 128, NQKV / 128), 256, 0, stream>>>(
        xnR, qkvT, qkvB, nullptr, F, NQKV, 256);
    // 3. deformable sampling + softmax + aggregation -> agg (reuses xn region)
    sample_kernel<<<Mrows / 4, 256, 0, stream>>>(F, refp, xnR);
    // 4. x2 = x + agg @ w_out + b_out -> d_out (f32)
    mfma_gemm<64, false, true, float><<<dim3(Mrows / 128, 256 / 64), 256, 0, stream>>>(
        xnR, woutT, b_out, x, out, 256, 256);
    // 5. LN2 -> y (bf16, reuses xn region)
    ln_kernel<unsigned short><<<Mrows, 256, 0, stream>>>(out, ln2_g, ln2_b, xnR);
    // 6. h = gelu(y @ w1 + b1) (bf16)
    mfma_gemm<128, true, false, unsigned short><<<dim3(Mrows / 128, 1024 / 128), 256, 0, stream>>>(
        xnR, w1T, b1, nullptr, h, 1024, 256);
    // 7. depthwise conv + gelu -> h2 (bf16)
    dwconv_kernel<<<Mrows / 4, 256, 0, stream>>>(h, wdwT, b_dw, h2);
    // 8. out = x2 + h2 @ w2 + b2 (f32, in-place residual)
    mfma_gemm<64, false, true, float><<<dim3(Mrows / 128, 256 / 64), 256, 0, stream>>>(
        h2, w2T, b2, out, out, 256, 1024);
}

// Round 8
// 166.884 us; speedup vs baseline: 1.0656x; 1.0187x over previous
//
#include <hip/hip_runtime.h>
#include <hip/hip_bf16.h>
#include <type_traits>

// Problem constants
constexpr int Bc = 2, Hc = 64, Wc = 128, Cc = 256;
constexpr int HEADS = 8, KPT = 9, HIDDEN = 1024;
constexpr int HD = Cc / HEADS;           // 32
constexpr int NPIX = Hc * Wc;            // 8192
constexpr int Mrows = Bc * NPIX;         // 16384
constexpr int NQKV = 512;                // 256 (v) + 144 (off) + 72 (attn) padded to 512

typedef __attribute__((ext_vector_type(4))) float f32x4;
typedef __attribute__((ext_vector_type(8))) short bf16x8;

__device__ __forceinline__ float bf2f(unsigned short u) {
    union { unsigned int i; float f; } c; c.i = ((unsigned int)u) << 16; return c.f;
}
__device__ __forceinline__ unsigned short f2bf(float f) {
    __hip_bfloat16 h = __float2bfloat16(f);
    return *reinterpret_cast<unsigned short*>(&h);
}
__device__ __forceinline__ float gelu_exact(float x) {
    return 0.5f * x * (1.0f + erff(x * 0.70710678118654752f));
}
__device__ __forceinline__ void gl2lds16(const void* g, void* l) {
    __builtin_amdgcn_global_load_lds(
        (const __attribute__((address_space(1))) unsigned int*)g,
        (__attribute__((address_space(3))) unsigned int*)l, 16, 0, 0);
}

// ---------------- LayerNorm over C=256, one row per 256-thread block ----------------
template<typename TO>
__global__ __launch_bounds__(256) void ln_kernel(const float* __restrict__ in,
        const float* __restrict__ g, const float* __restrict__ b,
        TO* __restrict__ out) {
    const int r = blockIdx.x;
    const int t = threadIdx.x;
    const size_t base = (size_t)r * Cc;
    float val = in[base + t];
    float s = val, s2 = val * val;
    #pragma unroll
    for (int o = 32; o > 0; o >>= 1) { s += __shfl_down(s, o); s2 += __shfl_down(s2, o); }
    __shared__ float ps[4], ps2[4];
    if ((t & 63) == 0) { ps[t >> 6] = s; ps2[t >> 6] = s2; }
    __syncthreads();
    const float ts  = ps[0] + ps[1] + ps[2] + ps[3];
    const float ts2 = ps2[0] + ps2[1] + ps2[2] + ps2[3];
    const float mean = ts * (1.0f / Cc);
    const float var  = ts2 * (1.0f / Cc) - mean * mean;
    const float rstd = rsqrtf(var + 1e-5f);
    const float v = (val - mean) * rstd * g[t] + b[t];
    if constexpr (std::is_same<TO, float>::value) out[base + t] = v;
    else out[base + t] = f2bf(v);
}

// ---------------- Weight prep: f32 [K,N] -> bf16 [N,K] (transposed), QKV fused+padded ----
// Also transposes depthwise weights [1024][9] -> [9][1024] f32 for coalesced loads.
__global__ __launch_bounds__(256) void prep_weights(
        const float* __restrict__ w_v, const float* __restrict__ b_v,
        const float* __restrict__ w_off, const float* __restrict__ b_off,
        const float* __restrict__ w_attn, const float* __restrict__ b_attn,
        const float* __restrict__ w_out, const float* __restrict__ w1,
        const float* __restrict__ w2, const float* __restrict__ w_dw,
        unsigned short* __restrict__ qkvT, float* __restrict__ qkvB,
        unsigned short* __restrict__ woutT, unsigned short* __restrict__ w1T,
        unsigned short* __restrict__ w2T, float* __restrict__ wdwT) {
    const int blk = blockIdx.x;
    const int t = threadIdx.x;
    if (blk < NQKV) {                      // qkvT row n, K=256
        const int n = blk;
        float val = 0.0f;
        if (n < 256)       val = w_v[t * 256 + n];
        else if (n < 400)  val = w_off[t * 144 + (n - 256)];
        else if (n < 472)  val = w_attn[t * 72 + (n - 400)];
        qkvT[n * 256 + t] = f2bf(val);
        if (t == 0) {
            float bv = 0.0f;
            if (n < 256)      bv = b_v[n];
            else if (n < 400) bv = b_off[n - 256];
            else if (n < 472) bv = b_attn[n - 400];
            qkvB[n] = bv;
        }
    } else if (blk < NQKV + 256) {         // woutT row n, K=256
        const int n = blk - NQKV;
        woutT[n * 256 + t] = f2bf(w_out[t * 256 + n]);
    } else if (blk < NQKV + 256 + 1024) {  // w1T row n, K=256
        const int n = blk - (NQKV + 256);
        w1T[n * 256 + t] = f2bf(w1[t * 1024 + n]);
    } else if (blk < NQKV + 256 + 1024 + 256) { // w2T row n, K=1024
        const int n = blk - (NQKV + 256 + 1024);
        #pragma unroll
        for (int k = t; k < 1024; k += 256)
            w2T[n * 1024 + k] = f2bf(w2[k * 256 + n]);
    } else {                               // wdwT row j (9 rows)
        const int j = blk - (NQKV + 256 + 1024 + 256);
        #pragma unroll
        for (int c = t; c < HIDDEN; c += 256)
            wdwT[j * HIDDEN + c] = w_dw[c * 9 + j];
    }
}

// ---------------- bf16 MFMA GEMM: Out[M,N] = A[M,K] @ BT[N,K]^T + bias ----------------
// Tile 128 x BN, BK=64, 256 threads (4 waves, 2x2 wave grid), 16x16x32 bf16 MFMA.
// Grid: blockIdx.x = row panel (fastest) -> same-row-panel blocks share one XCD L2.
// K-loop: T4 counted-vmcnt 2-tile-ahead pipeline (guide §5.5 m218): prologue stages
// tiles 0,1; each iter waits vmcnt(LA) (tile tt done, tile tt+1 STAYS IN FLIGHT),
// computes, then stages tile tt+2 into the just-freed buffer. Raw s_barrier +
// sched_barrier(0) (rule #18) instead of __syncthreads (which would drain vmcnt(0)).
// LDS per K-tile: [rows][64] bf16, XOR swizzle byte^=((row&7)<<4) via pre-swizzled src.
// Epilogue: C-tile staged in (now dead) LDS, then streamed out with dwordx4 stores.
template<int BN, bool GELU, bool RESID, typename TO>
__global__ __launch_bounds__(256) void mfma_gemm(
        const unsigned short* __restrict__ A,   // [M,K] bf16
        const unsigned short* __restrict__ BT,  // [N,K] bf16
        const float* __restrict__ bias,         // [N]
        const float* __restrict__ resid,        // [M,N] f32 (if RESID)
        TO* __restrict__ Out,                   // [M,N]
        int N, int K) {
    constexpr int NFR = BN / 32;                // B fragments per wave (128->4, 64->2)
    constexpr int BUFB = 16384 + BN * 128;      // A tile 16 KB + B tile (BN*64*2 B)
    // double buffer (BN=128: 64 KB, BN=64: 48 KB); epilogue C-tile (32 KB) reuses it.
    __shared__ __align__(16) char lds[2 * BUFB];
    const int t = threadIdx.x;
    const int w = t >> 6;
    const int l = t & 63;
    const int row0 = blockIdx.x * 128;
    const int col0 = blockIdx.y * BN;
    const int wr = (w >> 1) * 64;               // wave row offset in tile
    const int wc = (w & 1) * (BN / 2);          // wave col offset in tile

    // staging geometry: chunk = 8 rows x 64 cols (1024 B); lane l -> row c*8+l/8,
    // 16B slot (l%8); source slot is XOR-swizzled so LDS holds swizzled layout.
    const int srow = l >> 3;
    const int selem = ((l & 7) ^ srow) * 8;     // element offset of this lane's 16B

    auto stage = [&](char* buf, int k0) {       // LA = 4 + NFR loads per wave
        unsigned short* As_ = (unsigned short*)buf;
        unsigned short* Bs_ = (unsigned short*)(buf + 16384);
        #pragma unroll
        for (int i = 0; i < 4; ++i) {           // A tile: 16 chunks, 4 per wave
            const int c = w + i * 4;
            const int row = c * 8 + srow;
            gl2lds16(A + (size_t)(row0 + row) * K + k0 + selem, As_ + c * 512);
        }
        #pragma unroll
        for (int i = 0; i < NFR; ++i) {         // B tile: BN/8 chunks
            const int c = w + i * 4;
            const int row = c * 8 + srow;
            gl2lds16(BT + (size_t)(col0 + row) * K + k0 + selem, Bs_ + c * 512);
        }
    };

    f32x4 acc[4][NFR] = {};
    const int nt = K / 64;

    // prologue: stage tiles 0 and 1 (2-deep pipeline)
    stage(lds, 0);
    if (nt > 1) stage(lds + BUFB, 64);

    for (int tt = 0; tt < nt; ++tt) {
        // wait for tile tt's DMA only; tile tt+1's LA loads may stay outstanding
        if (tt + 1 < nt) {
            if constexpr (NFR == 4) asm volatile("s_waitcnt vmcnt(8)" ::: "memory");
            else                    asm volatile("s_waitcnt vmcnt(6)" ::: "memory");
        } else {
            asm volatile("s_waitcnt vmcnt(0)" ::: "memory");
        }
        __builtin_amdgcn_s_barrier();
        __builtin_amdgcn_sched_barrier(0);

        const char* Ab = lds + (size_t)(tt & 1) * BUFB;
        const char* Bb = Ab + 16384;
        #pragma unroll
        for (int ks = 0; ks < 2; ++ks) {
            const int kb = ks * 64 + (l >> 4) * 16;   // byte offset within 128B row
            bf16x8 af[4], bfr[NFR];
            #pragma unroll
            for (int mi = 0; mi < 4; ++mi) {
                const int row = wr + mi * 16 + (l & 15);
                af[mi] = *(const bf16x8*)(Ab + row * 128 + (kb ^ ((row & 7) << 4)));
            }
            #pragma unroll
            for (int ni = 0; ni < NFR; ++ni) {
                const int row = wc + ni * 16 + (l & 15);
                bfr[ni] = *(const bf16x8*)(Bb + row * 128 + (kb ^ ((row & 7) << 4)));
            }
            #pragma unroll
            for (int mi = 0; mi < 4; ++mi)
                #pragma unroll
                for (int ni = 0; ni < NFR; ++ni)
                    acc[mi][ni] = __builtin_amdgcn_mfma_f32_16x16x32_bf16(
                        af[mi], bfr[ni], acc[mi][ni], 0, 0, 0);
        }
        // all waves done reading buf[tt&1] (their ds_reads retired before last MFMA)
        __builtin_amdgcn_s_barrier();
        __builtin_amdgcn_sched_barrier(0);
        if (tt + 2 < nt) stage(lds + (size_t)(tt & 1) * BUFB, (tt + 2) * 64);
    }

    // ---- epilogue phase 1: stage C-tile into LDS (256 B per row, row-XOR swizzle) ----
    // MFMA C/D layout: col=l&15, row=(l>>4)*4+reg (guide §3, m89-verified)
    const int lrow = (l >> 4) * 4;
    const int lcol = l & 15;
    #pragma unroll
    for (int ni = 0; ni < NFR; ++ni) {
        const int col = wc + ni * 16 + lcol;            // tile-relative col
        const float bb = bias[col0 + col];
        #pragma unroll
        for (int mi = 0; mi < 4; ++mi) {
            #pragma unroll
            for (int r = 0; r < 4; ++r) {
                const int row = wr + mi * 16 + lrow + r;
                float v = acc[mi][ni][r] + bb;
                if constexpr (GELU) v = gelu_exact(v);
                if constexpr (std::is_same<TO, unsigned short>::value) {
                    *(unsigned short*)(lds + row * 256 + ((col * 2) ^ ((row & 7) << 4))) = f2bf(v);
                } else {
                    *(float*)(lds + row * 256 + ((col * 4) ^ ((row & 7) << 4))) = v;
                }
            }
        }
    }
    __syncthreads();
    // ---- epilogue phase 2: wide coalesced write-back (8 x 16B per thread) ----
    const int rr = t >> 1;                    // tile row (128 rows, 2 threads each)
    const int hf = t & 1;                     // which 128-byte half of the row
    if constexpr (std::is_same<TO, unsigned short>::value) {
        unsigned short* obase = Out + (size_t)(row0 + rr) * N + col0;
        #pragma unroll
        for (int i = 0; i < 8; ++i) {
            const int bo = hf * 128 + i * 16;
            const int4 val = *(const int4*)(lds + rr * 256 + (bo ^ ((rr & 7) << 4)));
            *(int4*)(obase + bo / 2) = val;
        }
    } else {
        float* obase = (float*)Out + (size_t)(row0 + rr) * N + col0;
        const float* rbase = RESID ? (resid + (size_t)(row0 + rr) * N + col0) : nullptr;
        #pragma unroll
        for (int i = 0; i < 8; ++i) {
            const int bo = hf * 128 + i * 16;
            float4 val = *(const float4*)(lds + rr * 256 + (bo ^ ((rr & 7) << 4)));
            if constexpr (RESID) {
                const float4 rv = *(const float4*)(rbase + bo / 4);
                val.x += rv.x; val.y += rv.y; val.z += rv.z; val.w += rv.w;
            }
            *(float4*)(obase + bo / 4) = val;
        }
    }
}

// ---------------- Deformable sampling + softmax + aggregation (bf16 in/out) ----------------
// F = fused QKV buffer [M, 512]: cols 0-255 v, 256-399 offsets, 400-471 attn logits.
// 4 pixels per block (one wave each); within a pixel, lane tl: head = tl>>3, quad = tl&7
// owns 4 channels -> 8 B gathers (8 lanes x 8 B = one 64 B segment per head-corner).
__global__ __launch_bounds__(256) void sample_kernel(const unsigned short* __restrict__ F,
        const float* __restrict__ refp, unsigned short* __restrict__ agg) {
    constexpr int PPB = 4;                       // pixels per block
    const int m0 = blockIdx.x * PPB;             // 8192 % 4 == 0 -> same batch for all 4
    const int b = m0 / NPIX;
    const int pix0 = m0 - b * NPIX;
    const int t = threadIdx.x;
    __shared__ int4   s_idx[PPB][72];
    __shared__ float4 s_w[PPB][72];
    __shared__ float  s_lg[PPB][72];

    // phase 1: coords + bilinear corners/weights + logits (288 items on 256 threads)
    for (int idx = t; idx < PPB * 72; idx += 256) {
        const int p = idx / 72, hk = idx - p * 72;
        const int head = hk / 9, k = hk - head * 9;
        const int m = m0 + p, pix = pix0 + p;
        const size_t fb = (size_t)m * NQKV;
        const unsigned int ou = *(const unsigned int*)(F + fb + 256 + head * 18 + k * 2);
        const float ox = __uint_as_float(ou << 16);
        const float oy = __uint_as_float(ou & 0xffff0000u);
        const float2 rr = *(const float2*)(refp + ((size_t)pix * KPT + k) * 2);
        const float cx = (rr.x + ox + 1.0f) * 0.5f * (Wc - 1);
        const float cy = (rr.y + oy + 1.0f) * 0.5f * (Hc - 1);
        const float fx = floorf(cx), fy = floorf(cy);
        const float wx = cx - fx, wy = cy - fy;
        const int x0 = min(max((int)fx, 0), Wc - 1);
        const int x1 = min(max((int)fx + 1, 0), Wc - 1);
        const int y0 = min(max((int)fy, 0), Hc - 1);
        const int y1 = min(max((int)fy + 1, 0), Hc - 1);
        s_idx[p][hk] = make_int4(y0 * Wc + x0, y0 * Wc + x1, y1 * Wc + x0, y1 * Wc + x1);
        s_w[p][hk] = make_float4((1.0f - wy) * (1.0f - wx), (1.0f - wy) * wx,
                                 wy * (1.0f - wx), wy * wx);
        s_lg[p][hk] = bf2f(F[fb + 400 + hk]);
    }
    __syncthreads();
    // phase 2: softmax over k per (p, head); premultiply attn into corner weights
    for (int idx = t; idx < PPB * 72; idx += 256) {
        const int p = idx / 72, hk = idx - p * 72;
        const int h9 = (hk / 9) * 9;
        float mx = -1e30f;
        #pragma unroll
        for (int k = 0; k < 9; ++k) mx = fmaxf(mx, s_lg[p][h9 + k]);
        float sm = 0.0f;
        #pragma unroll
        for (int k = 0; k < 9; ++k) sm += __expf(s_lg[p][h9 + k] - mx);
        const float a = __expf(s_lg[p][hk] - mx) / sm;
        float4 w = s_w[p][hk];
        w.x *= a; w.y *= a; w.z *= a; w.w *= a;
        s_w[p][hk] = w;
    }
    __syncthreads();
    // phase 3: gather-accumulate, 4 channels per lane
    const int p = t >> 6, tl = t & 63;
    const int head = tl >> 3, dq = tl & 7;
    const unsigned short* vb = F + (size_t)b * NPIX * NQKV + head * HD + dq * 4;
    float a0 = 0.f, a1 = 0.f, a2 = 0.f, a3 = 0.f;
    #pragma unroll
    for (int k = 0; k < 9; ++k) {
        const int hk = head * 9 + k;
        const int4   ix = s_idx[p][hk];
        const float4 ww = s_w[p][hk];
        {
            const uint2 u = *(const uint2*)(vb + (size_t)ix.x * NQKV);
            a0 += __uint_as_float(u.x << 16) * ww.x;
            a1 += __uint_as_float(u.x & 0xffff0000u) * ww.x;
            a2 += __uint_as_float(u.y << 16) * ww.x;
            a3 += __uint_as_float(u.y & 0xffff0000u) * ww.x;
        }
        {
            const uint2 u = *(const uint2*)(vb + (size_t)ix.y * NQKV);
            a0 += __uint_as_float(u.x << 16) * ww.y;
            a1 += __uint_as_float(u.x & 0xffff0000u) * ww.y;
            a2 += __uint_as_float(u.y << 16) * ww.y;
            a3 += __uint_as_float(u.y & 0xffff0000u) * ww.y;
        }
        {
            const uint2 u = *(const uint2*)(vb + (size_t)ix.z * NQKV);
            a0 += __uint_as_float(u.x << 16) * ww.z;
            a1 += __uint_as_float(u.x & 0xffff0000u) * ww.z;
            a2 += __uint_as_float(u.y << 16) * ww.z;
            a3 += __uint_as_float(u.y & 0xffff0000u) * ww.z;
        }
        {
            const uint2 u = *(const uint2*)(vb + (size_t)ix.w * NQKV);
            a0 += __uint_as_float(u.x << 16) * ww.w;
            a1 += __uint_as_float(u.x & 0xffff0000u) * ww.w;
            a2 += __uint_as_float(u.y << 16) * ww.w;
            a3 += __uint_as_float(u.y & 0xffff0000u) * ww.w;
        }
    }
    ushort4 o;
    o.x = f2bf(a0); o.y = f2bf(a1); o.z = f2bf(a2); o.w = f2bf(a3);
    *reinterpret_cast<ushort4*>(agg + (size_t)(m0 + p) * Cc + tl * 4) = o;
}

// ---------------- Depthwise 3x3 conv (circular W, zero H) + GELU, bf16 in/out ----------------
// Quad-of-pixels per block: each block computes 4 consecutive x positions for all 1024
// channels; thread t owns channels [4t,4t+4) for all 4 outputs. Loads 3 rows x 6 cols
// (18 independent ushort4 per thread) -> 2x less L2 traffic + 4x ILP vs 1-pixel blocks.
__global__ __launch_bounds__(256) void dwconv_kernel(const unsigned short* __restrict__ h,
        const float* __restrict__ wdwT, const float* __restrict__ bdw,
        unsigned short* __restrict__ h2) {
    constexpr int NQ = 4;                     // x-positions per block
    constexpr int nblk = Mrows / NQ;          // 4096
    const int bid = blockIdx.x;
    const int qi = (bid & 7) * (nblk / 8) + (bid >> 3);   // XCD-chunked swizzle (4096 % 8 == 0)
    const int m0 = qi * NQ;                   // quad never crosses a row (Wc % NQ == 0)
    const int b = m0 / NPIX;
    const int pix0 = m0 - b * NPIX;
    const int y = pix0 / Wc, x0 = pix0 - y * Wc;
    const int t = threadIdx.x;
    const int c0 = t * 4;

    float wreg[9][4];
    #pragma unroll
    for (int j = 0; j < 9; ++j) {
        const float4 wv = *reinterpret_cast<const float4*>(wdwT + j * HIDDEN + c0);
        wreg[j][0] = wv.x; wreg[j][1] = wv.y; wreg[j][2] = wv.z; wreg[j][3] = wv.w;
    }

    float acc[NQ][4] = {};
    #pragma unroll
    for (int dy = -1; dy <= 1; ++dy) {
        const int yy = y + dy;
        if (yy < 0 || yy >= Hc) continue;     // zero pad along height (block-uniform branch)
        const size_t rowbase = ((size_t)b * NPIX + (size_t)yy * Wc) * HIDDEN + c0;
        #pragma unroll
        for (int j = 0; j < NQ + 2; ++j) {    // columns x0-1 .. x0+NQ (circular)
            const int xx = (x0 + j - 1 + Wc) & (Wc - 1);
            const ushort4 hv = *reinterpret_cast<const ushort4*>(h + rowbase + (size_t)xx * HIDDEN);
            const float f0 = bf2f(hv.x), f1 = bf2f(hv.y), f2 = bf2f(hv.z), f3 = bf2f(hv.w);
            #pragma unroll
            for (int q = 0; q < NQ; ++q) {
                if (q >= j - 2 && q <= j) {   // folds to constants after unroll
                    const int wj = (dy + 1) * 3 + (j - q);
                    acc[q][0] += f0 * wreg[wj][0];
                    acc[q][1] += f1 * wreg[wj][1];
                    acc[q][2] += f2 * wreg[wj][2];
                    acc[q][3] += f3 * wreg[wj][3];
                }
            }
        }
    }
    const float4 bb = *reinterpret_cast<const float4*>(bdw + c0);
    #pragma unroll
    for (int q = 0; q < NQ; ++q) {
        ushort4 o;
        o.x = f2bf(gelu_exact(acc[q][0] + bb.x));
        o.y = f2bf(gelu_exact(acc[q][1] + bb.y));
        o.z = f2bf(gelu_exact(acc[q][2] + bb.z));
        o.w = f2bf(gelu_exact(acc[q][3] + bb.w));
        *reinterpret_cast<ushort4*>(h2 + (size_t)(m0 + q) * HIDDEN + c0) = o;
    }
}

extern "C" void kernel_launch(void* const* d_in, const int* in_sizes, int n_in,
                              void* d_out, int out_size, void* d_ws, size_t ws_size,
                              hipStream_t stream) {
    const float* x      = (const float*)d_in[0];
    const float* refp   = (const float*)d_in[1];
    const float* ln1_g  = (const float*)d_in[2];
    const float* ln1_b  = (const float*)d_in[3];
    const float* w_v    = (const float*)d_in[4];
    const float* b_v    = (const float*)d_in[5];
    const float* w_off  = (const float*)d_in[6];
    const float* b_off  = (const float*)d_in[7];
    const float* w_attn = (const float*)d_in[8];
    const float* b_attn = (const float*)d_in[9];
    const float* w_out  = (const float*)d_in[10];
    const float* b_out  = (const float*)d_in[11];
    const float* ln2_g  = (const float*)d_in[12];
    const float* ln2_b  = (const float*)d_in[13];
    const float* w1     = (const float*)d_in[14];
    const float* b1     = (const float*)d_in[15];
    const float* w_dw   = (const float*)d_in[16];
    const float* b_dw   = (const float*)d_in[17];
    const float* w2     = (const float*)d_in[18];
    const float* b2     = (const float*)d_in[19];
    float* out = (float*)d_out;

    // Workspace layout (bytes); lifetimes make the overlaps safe:
    //  [0,  8M): xn -> agg -> y          (bf16 [M,256], sequential reuse)
    //  [8, 24M): F fused qkv (bf16 [M,512]) — dead after sample_kernel
    //  [8, 40M): h (bf16 [M,1024])       — written after F is dead
    //  [40,72M): h2 (bf16 [M,1024])
    //  [72M,..): transposed bf16 weights + wdwT + fused qkv bias
    char* wsb = (char*)d_ws;
    unsigned short* xnR = (unsigned short*)(wsb);
    unsigned short* F   = (unsigned short*)(wsb + (8ull  << 20));
    unsigned short* h   = (unsigned short*)(wsb + (8ull  << 20));
    unsigned short* h2  = (unsigned short*)(wsb + (40ull << 20));
    size_t woff = 72ull << 20;
    unsigned short* qkvT = (unsigned short*)(wsb + woff); woff += (size_t)NQKV * 256 * 2;
    unsigned short* woutT= (unsigned short*)(wsb + woff); woff += 256 * 256 * 2;
    unsigned short* w1T  = (unsigned short*)(wsb + woff); woff += 1024 * 256 * 2;
    unsigned short* w2T  = (unsigned short*)(wsb + woff); woff += 256 * 1024 * 2;
    float*          wdwT = (float*)(wsb + woff);          woff += 9 * 1024 * 4;
    float*          qkvB = (float*)(wsb + woff);

    // 0. weight transpose/convert (independent of activations)
    prep_weights<<<NQKV + 256 + 1024 + 256 + 9, 256, 0, stream>>>(
        w_v, b_v, w_off, b_off, w_attn, b_attn, w_out, w1, w2, w_dw,
        qkvT, qkvB, woutT, w1T, w2T, wdwT);
    // 1. LN1 -> xn (bf16)
    ln_kernel<unsigned short><<<Mrows, 256, 0, stream>>>(x, ln1_g, ln1_b, xnR);
    // 2. fused QKV GEMM: F = xn @ [w_v|w_off|w_attn] + bias  (bf16 out)
    mfma_gemm<128, false, false, unsigned short><<<dim3(Mrows / 128, NQKV / 128), 256, 0, stream>>>(
        xnR, qkvT, qkvB, nullptr, F, NQKV, 256);
    // 3. deformable sampling + softmax + aggregation -> agg (reuses xn region)
    sample_kernel<<<Mrows / 4, 256, 0, stream>>>(F, refp, xnR);
    // 4. x2 = x + agg @ w_out + b_out -> d_out (f32)
    mfma_gemm<64, false, true, float><<<dim3(Mrows / 128, 256 / 64), 256, 0, stream>>>(
        xnR, woutT, b_out, x, out, 256, 256);
    // 5. LN2 -> y (bf16, reuses xn region)
    ln_kernel<unsigned short><<<Mrows, 256, 0, stream>>>(out, ln2_g, ln2_b, xnR);
    // 6. h = gelu(y @ w1 + b1) (bf16)
    mfma_gemm<128, true, false, unsigned short><<<dim3(Mrows / 128, 1024 / 128), 256, 0, stream>>>(
        xnR, w1T, b1, nullptr, h, 1024, 256);
    // 7. depthwise conv + gelu -> h2 (bf16)
    dwconv_kernel<<<Mrows / 4, 256, 0, stream>>>(h, wdwT, b_dw, h2);
    // 8. out = x2 + h2 @ w2 + b2 (f32, in-place residual)
    mfma_gemm<64, false, true, float><<<dim3(Mrows / 128, 256 / 64), 256, 0, stream>>>(
        h2, w2T, b2, out, out, 256, 1024);
}

// Round 9
// 147.518 us; speedup vs baseline: 1.2054x; 1.1313x over previous
//
#include <hip/hip_runtime.h>
#include <hip/hip_bf16.h>
#include <type_traits>

// Problem constants
constexpr int Bc = 2, Hc = 64, Wc = 128, Cc = 256;
constexpr int HEADS = 8, KPT = 9, HIDDEN = 1024;
constexpr int HD = Cc / HEADS;           // 32
constexpr int NPIX = Hc * Wc;            // 8192
constexpr int Mrows = Bc * NPIX;         // 16384
constexpr int NQKV = 512;                // 256 (v) + 144 (off) + 72 (attn) padded to 512

typedef __attribute__((ext_vector_type(4))) float f32x4;
typedef __attribute__((ext_vector_type(8))) short bf16x8;

__device__ __forceinline__ float bf2f(unsigned short u) {
    union { unsigned int i; float f; } c; c.i = ((unsigned int)u) << 16; return c.f;
}
__device__ __forceinline__ unsigned short f2bf(float f) {
    __hip_bfloat16 h = __float2bfloat16(f);
    return *reinterpret_cast<unsigned short*>(&h);
}
__device__ __forceinline__ float gelu_exact(float x) {
    return 0.5f * x * (1.0f + erff(x * 0.70710678118654752f));
}
__device__ __forceinline__ void gl2lds16(const void* g, void* l) {
    __builtin_amdgcn_global_load_lds(
        (const __attribute__((address_space(1))) unsigned int*)g,
        (__attribute__((address_space(3))) unsigned int*)l, 16, 0, 0);
}

// ---------------- LayerNorm over C=256, one row per 256-thread block ----------------
template<typename TO>
__global__ __launch_bounds__(256) void ln_kernel(const float* __restrict__ in,
        const float* __restrict__ g, const float* __restrict__ b,
        TO* __restrict__ out) {
    const int r = blockIdx.x;
    const int t = threadIdx.x;
    const size_t base = (size_t)r * Cc;
    float val = in[base + t];
    float s = val, s2 = val * val;
    #pragma unroll
    for (int o = 32; o > 0; o >>= 1) { s += __shfl_down(s, o); s2 += __shfl_down(s2, o); }
    __shared__ float ps[4], ps2[4];
    if ((t & 63) == 0) { ps[t >> 6] = s; ps2[t >> 6] = s2; }
    __syncthreads();
    const float ts  = ps[0] + ps[1] + ps[2] + ps[3];
    const float ts2 = ps2[0] + ps2[1] + ps2[2] + ps2[3];
    const float mean = ts * (1.0f / Cc);
    const float var  = ts2 * (1.0f / Cc) - mean * mean;
    const float rstd = rsqrtf(var + 1e-5f);
    const float v = (val - mean) * rstd * g[t] + b[t];
    if constexpr (std::is_same<TO, float>::value) out[base + t] = v;
    else out[base + t] = f2bf(v);
}

// ---------------- Weight prep: f32 [K,N] -> bf16 [N,K] (transposed), QKV fused+padded ----
// Also transposes depthwise weights [1024][9] -> [9][1024] f32 for coalesced loads.
__global__ __launch_bounds__(256) void prep_weights(
        const float* __restrict__ w_v, const float* __restrict__ b_v,
        const float* __restrict__ w_off, const float* __restrict__ b_off,
        const float* __restrict__ w_attn, const float* __restrict__ b_attn,
        const float* __restrict__ w_out, const float* __restrict__ w1,
        const float* __restrict__ w2, const float* __restrict__ w_dw,
        unsigned short* __restrict__ qkvT, float* __restrict__ qkvB,
        unsigned short* __restrict__ woutT, unsigned short* __restrict__ w1T,
        unsigned short* __restrict__ w2T, float* __restrict__ wdwT) {
    const int blk = blockIdx.x;
    const int t = threadIdx.x;
    if (blk < NQKV) {                      // qkvT row n, K=256
        const int n = blk;
        float val = 0.0f;
        if (n < 256)       val = w_v[t * 256 + n];
        else if (n < 400)  val = w_off[t * 144 + (n - 256)];
        else if (n < 472)  val = w_attn[t * 72 + (n - 400)];
        qkvT[n * 256 + t] = f2bf(val);
        if (t == 0) {
            float bv = 0.0f;
            if (n < 256)      bv = b_v[n];
            else if (n < 400) bv = b_off[n - 256];
            else if (n < 472) bv = b_attn[n - 400];
            qkvB[n] = bv;
        }
    } else if (blk < NQKV + 256) {         // woutT row n, K=256
        const int n = blk - NQKV;
        woutT[n * 256 + t] = f2bf(w_out[t * 256 + n]);
    } else if (blk < NQKV + 256 + 1024) {  // w1T row n, K=256
        const int n = blk - (NQKV + 256);
        w1T[n * 256 + t] = f2bf(w1[t * 1024 + n]);
    } else if (blk < NQKV + 256 + 1024 + 256) { // w2T row n, K=1024
        const int n = blk - (NQKV + 256 + 1024);
        #pragma unroll
        for (int k = t; k < 1024; k += 256)
            w2T[n * 1024 + k] = f2bf(w2[k * 256 + n]);
    } else {                               // wdwT row j (9 rows)
        const int j = blk - (NQKV + 256 + 1024 + 256);
        #pragma unroll
        for (int c = t; c < HIDDEN; c += 256)
            wdwT[j * HIDDEN + c] = w_dw[c * 9 + j];
    }
}

// ---------------- bf16 MFMA GEMM: Out[M,N] = A[M,K] @ BT[N,K]^T + bias ----------------
// Tile 128 x BN, BK=64, 256 threads (4 waves, 2x2 wave grid), 16x16x32 bf16 MFMA.
// Grid: blockIdx.x = row panel (fastest) -> same-row-panel blocks share one XCD L2.
// K-loop: counted-vmcnt 2-tile-ahead pipeline (T4). Epilogue: C-tile staged in the
// (now dead) LDS, then written back FULL-SECTOR: one store instruction = 4 complete
// 256 B rows (16 lanes x 16 B contiguous per row), so every 64 B HBM sector is
// produced by a single instruction -> no partial-sector write amplification
// (R4-R8 counters showed WRITE 2-4x ideal with the old 2-lanes-per-row mapping).
template<int BN, bool GELU, bool RESID, typename TO>
__global__ __launch_bounds__(256) void mfma_gemm(
        const unsigned short* __restrict__ A,   // [M,K] bf16
        const unsigned short* __restrict__ BT,  // [N,K] bf16
        const float* __restrict__ bias,         // [N]
        const float* __restrict__ resid,        // [M,N] f32 (if RESID)
        TO* __restrict__ Out,                   // [M,N]
        int N, int K) {
    constexpr int NFR = BN / 32;                // B fragments per wave (128->4, 64->2)
    constexpr int BUFB = 16384 + BN * 128;      // A tile 16 KB + B tile (BN*64*2 B)
    // double buffer (BN=128: 64 KB, BN=64: 48 KB); epilogue C-tile (32 KB) reuses it.
    __shared__ __align__(16) char lds[2 * BUFB];
    const int t = threadIdx.x;
    const int w = t >> 6;
    const int l = t & 63;
    const int row0 = blockIdx.x * 128;
    const int col0 = blockIdx.y * BN;
    const int wr = (w >> 1) * 64;               // wave row offset in tile
    const int wc = (w & 1) * (BN / 2);          // wave col offset in tile

    // staging geometry: chunk = 8 rows x 64 cols (1024 B); lane l -> row c*8+l/8,
    // 16B slot (l%8); source slot is XOR-swizzled so LDS holds swizzled layout.
    const int srow = l >> 3;
    const int selem = ((l & 7) ^ srow) * 8;     // element offset of this lane's 16B

    auto stage = [&](char* buf, int k0) {       // LA = 4 + NFR loads per wave
        unsigned short* As_ = (unsigned short*)buf;
        unsigned short* Bs_ = (unsigned short*)(buf + 16384);
        #pragma unroll
        for (int i = 0; i < 4; ++i) {           // A tile: 16 chunks, 4 per wave
            const int c = w + i * 4;
            const int row = c * 8 + srow;
            gl2lds16(A + (size_t)(row0 + row) * K + k0 + selem, As_ + c * 512);
        }
        #pragma unroll
        for (int i = 0; i < NFR; ++i) {         // B tile: BN/8 chunks
            const int c = w + i * 4;
            const int row = c * 8 + srow;
            gl2lds16(BT + (size_t)(col0 + row) * K + k0 + selem, Bs_ + c * 512);
        }
    };

    f32x4 acc[4][NFR] = {};
    const int nt = K / 64;

    // prologue: stage tiles 0 and 1 (2-deep pipeline)
    stage(lds, 0);
    if (nt > 1) stage(lds + BUFB, 64);

    for (int tt = 0; tt < nt; ++tt) {
        // wait for tile tt's DMA only; tile tt+1's LA loads may stay outstanding
        if (tt + 1 < nt) {
            if constexpr (NFR == 4) asm volatile("s_waitcnt vmcnt(8)" ::: "memory");
            else                    asm volatile("s_waitcnt vmcnt(6)" ::: "memory");
        } else {
            asm volatile("s_waitcnt vmcnt(0)" ::: "memory");
        }
        __builtin_amdgcn_s_barrier();
        __builtin_amdgcn_sched_barrier(0);

        const char* Ab = lds + (size_t)(tt & 1) * BUFB;
        const char* Bb = Ab + 16384;
        #pragma unroll
        for (int ks = 0; ks < 2; ++ks) {
            const int kb = ks * 64 + (l >> 4) * 16;   // byte offset within 128B row
            bf16x8 af[4], bfr[NFR];
            #pragma unroll
            for (int mi = 0; mi < 4; ++mi) {
                const int row = wr + mi * 16 + (l & 15);
                af[mi] = *(const bf16x8*)(Ab + row * 128 + (kb ^ ((row & 7) << 4)));
            }
            #pragma unroll
            for (int ni = 0; ni < NFR; ++ni) {
                const int row = wc + ni * 16 + (l & 15);
                bfr[ni] = *(const bf16x8*)(Bb + row * 128 + (kb ^ ((row & 7) << 4)));
            }
            #pragma unroll
            for (int mi = 0; mi < 4; ++mi)
                #pragma unroll
                for (int ni = 0; ni < NFR; ++ni)
                    acc[mi][ni] = __builtin_amdgcn_mfma_f32_16x16x32_bf16(
                        af[mi], bfr[ni], acc[mi][ni], 0, 0, 0);
        }
        // all waves done reading buf[tt&1] (their ds_reads retired before last MFMA)
        __builtin_amdgcn_s_barrier();
        __builtin_amdgcn_sched_barrier(0);
        if (tt + 2 < nt) stage(lds + (size_t)(tt & 1) * BUFB, (tt + 2) * 64);
    }

    // ---- epilogue phase 1: stage C-tile into LDS (256 B per row, row-XOR swizzle) ----
    // MFMA C/D layout: col=l&15, row=(l>>4)*4+reg (guide §3, m89-verified)
    const int lrow = (l >> 4) * 4;
    const int lcol = l & 15;
    #pragma unroll
    for (int ni = 0; ni < NFR; ++ni) {
        const int col = wc + ni * 16 + lcol;            // tile-relative col
        const float bb = bias[col0 + col];
        #pragma unroll
        for (int mi = 0; mi < 4; ++mi) {
            #pragma unroll
            for (int r = 0; r < 4; ++r) {
                const int row = wr + mi * 16 + lrow + r;
                float v = acc[mi][ni][r] + bb;
                if constexpr (GELU) v = gelu_exact(v);
                if constexpr (std::is_same<TO, unsigned short>::value) {
                    *(unsigned short*)(lds + row * 256 + ((col * 2) ^ ((row & 7) << 4))) = f2bf(v);
                } else {
                    *(float*)(lds + row * 256 + ((col * 4) ^ ((row & 7) << 4))) = v;
                }
            }
        }
    }
    __syncthreads();
    // ---- epilogue phase 2: full-sector write-back ----
    // 16 lanes cover one complete 256 B row; one instruction = rows [16*it+t/16]
    // fully contiguous -> every 64 B sector written by a single instruction.
    const int ck = t & 15;                    // 16 B chunk within the 256 B row
    #pragma unroll
    for (int it = 0; it < 8; ++it) {
        const int row = (t >> 4) + it * 16;
        const int bo = ck * 16;
        if constexpr (std::is_same<TO, unsigned short>::value) {
            const int4 val = *(const int4*)(lds + row * 256 + (bo ^ ((row & 7) << 4)));
            *(int4*)(Out + (size_t)(row0 + row) * N + col0 + bo / 2) = val;
        } else {
            float4 val = *(const float4*)(lds + row * 256 + (bo ^ ((row & 7) << 4)));
            if constexpr (RESID) {
                const float4 rv = *(const float4*)(resid + (size_t)(row0 + row) * N + col0 + bo / 4);
                val.x += rv.x; val.y += rv.y; val.z += rv.z; val.w += rv.w;
            }
            *(float4*)((float*)Out + (size_t)(row0 + row) * N + col0 + bo / 4) = val;
        }
    }
}

// ---------------- Deformable sampling + softmax + aggregation (bf16 in/out) ----------------
// F = fused QKV buffer [M, 512]: cols 0-255 v, 256-399 offsets, 400-471 attn logits.
// 4 pixels per block (one wave each); within a pixel, lane tl: head = tl>>3, quad = tl&7
// owns 4 channels -> 8 B gathers (8 lanes x 8 B = one 64 B segment per head-corner).
__global__ __launch_bounds__(256) void sample_kernel(const unsigned short* __restrict__ F,
        const float* __restrict__ refp, unsigned short* __restrict__ agg) {
    constexpr int PPB = 4;                       // pixels per block
    const int m0 = blockIdx.x * PPB;             // 8192 % 4 == 0 -> same batch for all 4
    const int b = m0 / NPIX;
    const int pix0 = m0 - b * NPIX;
    const int t = threadIdx.x;
    __shared__ int4   s_idx[PPB][72];
    __shared__ float4 s_w[PPB][72];
    __shared__ float  s_lg[PPB][72];

    // phase 1: coords + bilinear corners/weights + logits (288 items on 256 threads)
    for (int idx = t; idx < PPB * 72; idx += 256) {
        const int p = idx / 72, hk = idx - p * 72;
        const int head = hk / 9, k = hk - head * 9;
        const int m = m0 + p, pix = pix0 + p;
        const size_t fb = (size_t)m * NQKV;
        const unsigned int ou = *(const unsigned int*)(F + fb + 256 + head * 18 + k * 2);
        const float ox = __uint_as_float(ou << 16);
        const float oy = __uint_as_float(ou & 0xffff0000u);
        const float2 rr = *(const float2*)(refp + ((size_t)pix * KPT + k) * 2);
        const float cx = (rr.x + ox + 1.0f) * 0.5f * (Wc - 1);
        const float cy = (rr.y + oy + 1.0f) * 0.5f * (Hc - 1);
        const float fx = floorf(cx), fy = floorf(cy);
        const float wx = cx - fx, wy = cy - fy;
        const int x0 = min(max((int)fx, 0), Wc - 1);
        const int x1 = min(max((int)fx + 1, 0), Wc - 1);
        const int y0 = min(max((int)fy, 0), Hc - 1);
        const int y1 = min(max((int)fy + 1, 0), Hc - 1);
        s_idx[p][hk] = make_int4(y0 * Wc + x0, y0 * Wc + x1, y1 * Wc + x0, y1 * Wc + x1);
        s_w[p][hk] = make_float4((1.0f - wy) * (1.0f - wx), (1.0f - wy) * wx,
                                 wy * (1.0f - wx), wy * wx);
        s_lg[p][hk] = bf2f(F[fb + 400 + hk]);
    }
    __syncthreads();
    // phase 2: softmax over k per (p, head); premultiply attn into corner weights
    for (int idx = t; idx < PPB * 72; idx += 256) {
        const int p = idx / 72, hk = idx - p * 72;
        const int h9 = (hk / 9) * 9;
        float mx = -1e30f;
        #pragma unroll
        for (int k = 0; k < 9; ++k) mx = fmaxf(mx, s_lg[p][h9 + k]);
        float sm = 0.0f;
        #pragma unroll
        for (int k = 0; k < 9; ++k) sm += __expf(s_lg[p][h9 + k] - mx);
        const float a = __expf(s_lg[p][hk] - mx) / sm;
        float4 w = s_w[p][hk];
        w.x *= a; w.y *= a; w.z *= a; w.w *= a;
        s_w[p][hk] = w;
    }
    __syncthreads();
    // phase 3: gather-accumulate, 4 channels per lane
    const int p = t >> 6, tl = t & 63;
    const int head = tl >> 3, dq = tl & 7;
    const unsigned short* vb = F + (size_t)b * NPIX * NQKV + head * HD + dq * 4;
    float a0 = 0.f, a1 = 0.f, a2 = 0.f, a3 = 0.f;
    #pragma unroll
    for (int k = 0; k < 9; ++k) {
        const int hk = head * 9 + k;
        const int4   ix = s_idx[p][hk];
        const float4 ww = s_w[p][hk];
        {
            const uint2 u = *(const uint2*)(vb + (size_t)ix.x * NQKV);
            a0 += __uint_as_float(u.x << 16) * ww.x;
            a1 += __uint_as_float(u.x & 0xffff0000u) * ww.x;
            a2 += __uint_as_float(u.y << 16) * ww.x;
            a3 += __uint_as_float(u.y & 0xffff0000u) * ww.x;
        }
        {
            const uint2 u = *(const uint2*)(vb + (size_t)ix.y * NQKV);
            a0 += __uint_as_float(u.x << 16) * ww.y;
            a1 += __uint_as_float(u.x & 0xffff0000u) * ww.y;
            a2 += __uint_as_float(u.y << 16) * ww.y;
            a3 += __uint_as_float(u.y & 0xffff0000u) * ww.y;
        }
        {
            const uint2 u = *(const uint2*)(vb + (size_t)ix.z * NQKV);
            a0 += __uint_as_float(u.x << 16) * ww.z;
            a1 += __uint_as_float(u.x & 0xffff0000u) * ww.z;
            a2 += __uint_as_float(u.y << 16) * ww.z;
            a3 += __uint_as_float(u.y & 0xffff0000u) * ww.z;
        }
        {
            const uint2 u = *(const uint2*)(vb + (size_t)ix.w * NQKV);
            a0 += __uint_as_float(u.x << 16) * ww.w;
            a1 += __uint_as_float(u.x & 0xffff0000u) * ww.w;
            a2 += __uint_as_float(u.y << 16) * ww.w;
            a3 += __uint_as_float(u.y & 0xffff0000u) * ww.w;
        }
    }
    ushort4 o;
    o.x = f2bf(a0); o.y = f2bf(a1); o.z = f2bf(a2); o.w = f2bf(a3);
    *reinterpret_cast<ushort4*>(agg + (size_t)(m0 + p) * Cc + tl * 4) = o;
}

// ---------------- Depthwise 3x3 conv (circular W, zero H) + GELU, bf16 in/out ----------------
// Quad-of-pixels per block: each block computes 4 consecutive x positions for all 1024
// channels; thread t owns channels [4t,4t+4) for all 4 outputs. Loads 3 rows x 6 cols
// (18 independent ushort4 per thread) -> 2x less L2 traffic + 4x ILP vs 1-pixel blocks.
__global__ __launch_bounds__(256) void dwconv_kernel(const unsigned short* __restrict__ h,
        const float* __restrict__ wdwT, const float* __restrict__ bdw,
        unsigned short* __restrict__ h2) {
    constexpr int NQ = 4;                     // x-positions per block
    constexpr int nblk = Mrows / NQ;          // 4096
    const int bid = blockIdx.x;
    const int qi = (bid & 7) * (nblk / 8) + (bid >> 3);   // XCD-chunked swizzle (4096 % 8 == 0)
    const int m0 = qi * NQ;                   // quad never crosses a row (Wc % NQ == 0)
    const int b = m0 / NPIX;
    const int pix0 = m0 - b * NPIX;
    const int y = pix0 / Wc, x0 = pix0 - y * Wc;
    const int t = threadIdx.x;
    const int c0 = t * 4;

    float wreg[9][4];
    #pragma unroll
    for (int j = 0; j < 9; ++j) {
        const float4 wv = *reinterpret_cast<const float4*>(wdwT + j * HIDDEN + c0);
        wreg[j][0] = wv.x; wreg[j][1] = wv.y; wreg[j][2] = wv.z; wreg[j][3] = wv.w;
    }

    float acc[NQ][4] = {};
    #pragma unroll
    for (int dy = -1; dy <= 1; ++dy) {
        const int yy = y + dy;
        if (yy < 0 || yy >= Hc) continue;     // zero pad along height (block-uniform branch)
        const size_t rowbase = ((size_t)b * NPIX + (size_t)yy * Wc) * HIDDEN + c0;
        #pragma unroll
        for (int j = 0; j < NQ + 2; ++j) {    // columns x0-1 .. x0+NQ (circular)
            const int xx = (x0 + j - 1 + Wc) & (Wc - 1);
            const ushort4 hv = *reinterpret_cast<const ushort4*>(h + rowbase + (size_t)xx * HIDDEN);
            const float f0 = bf2f(hv.x), f1 = bf2f(hv.y), f2 = bf2f(hv.z), f3 = bf2f(hv.w);
            #pragma unroll
            for (int q = 0; q < NQ; ++q) {
                if (q >= j - 2 && q <= j) {   // folds to constants after unroll
                    const int wj = (dy + 1) * 3 + (j - q);
                    acc[q][0] += f0 * wreg[wj][0];
                    acc[q][1] += f1 * wreg[wj][1];
                    acc[q][2] += f2 * wreg[wj][2];
                    acc[q][3] += f3 * wreg[wj][3];
                }
            }
        }
    }
    const float4 bb = *reinterpret_cast<const float4*>(bdw + c0);
    #pragma unroll
    for (int q = 0; q < NQ; ++q) {
        ushort4 o;
        o.x = f2bf(gelu_exact(acc[q][0] + bb.x));
        o.y = f2bf(gelu_exact(acc[q][1] + bb.y));
        o.z = f2bf(gelu_exact(acc[q][2] + bb.z));
        o.w = f2bf(gelu_exact(acc[q][3] + bb.w));
        *reinterpret_cast<ushort4*>(h2 + (size_t)(m0 + q) * HIDDEN + c0) = o;
    }
}

extern "C" void kernel_launch(void* const* d_in, const int* in_sizes, int n_in,
                              void* d_out, int out_size, void* d_ws, size_t ws_size,
                              hipStream_t stream) {
    const float* x      = (const float*)d_in[0];
    const float* refp   = (const float*)d_in[1];
    const float* ln1_g  = (const float*)d_in[2];
    const float* ln1_b  = (const float*)d_in[3];
    const float* w_v    = (const float*)d_in[4];
    const float* b_v    = (const float*)d_in[5];
    const float* w_off  = (const float*)d_in[6];
    const float* b_off  = (const float*)d_in[7];
    const float* w_attn = (const float*)d_in[8];
    const float* b_attn = (const float*)d_in[9];
    const float* w_out  = (const float*)d_in[10];
    const float* b_out  = (const float*)d_in[11];
    const float* ln2_g  = (const float*)d_in[12];
    const float* ln2_b  = (const float*)d_in[13];
    const float* w1     = (const float*)d_in[14];
    const float* b1     = (const float*)d_in[15];
    const float* w_dw   = (const float*)d_in[16];
    const float* b_dw   = (const float*)d_in[17];
    const float* w2     = (const float*)d_in[18];
    const float* b2     = (const float*)d_in[19];
    float* out = (float*)d_out;

    // Workspace layout (bytes); lifetimes make the overlaps safe:
    //  [0,  8M): xn -> agg -> y          (bf16 [M,256], sequential reuse)
    //  [8, 24M): F fused qkv (bf16 [M,512]) — dead after sample_kernel
    //  [8, 40M): h (bf16 [M,1024])       — written after F is dead
    //  [40,72M): h2 (bf16 [M,1024])
    //  [72M,..): transposed bf16 weights + wdwT + fused qkv bias
    char* wsb = (char*)d_ws;
    unsigned short* xnR = (unsigned short*)(wsb);
    unsigned short* F   = (unsigned short*)(wsb + (8ull  << 20));
    unsigned short* h   = (unsigned short*)(wsb + (8ull  << 20));
    unsigned short* h2  = (unsigned short*)(wsb + (40ull << 20));
    size_t woff = 72ull << 20;
    unsigned short* qkvT = (unsigned short*)(wsb + woff); woff += (size_t)NQKV * 256 * 2;
    unsigned short* woutT= (unsigned short*)(wsb + woff); woff += 256 * 256 * 2;
    unsigned short* w1T  = (unsigned short*)(wsb + woff); woff += 1024 * 256 * 2;
    unsigned short* w2T  = (unsigned short*)(wsb + woff); woff += 256 * 1024 * 2;
    float*          wdwT = (float*)(wsb + woff);          woff += 9 * 1024 * 4;
    float*          qkvB = (float*)(wsb + woff);

    // 0. weight transpose/convert (independent of activations)
    prep_weights<<<NQKV + 256 + 1024 + 256 + 9, 256, 0, stream>>>(
        w_v, b_v, w_off, b_off, w_attn, b_attn, w_out, w1, w2, w_dw,
        qkvT, qkvB, woutT, w1T, w2T, wdwT);
    // 1. LN1 -> xn (bf16)
    ln_kernel<unsigned short><<<Mrows, 256, 0, stream>>>(x, ln1_g, ln1_b, xnR);
    // 2. fused QKV GEMM: F = xn @ [w_v|w_off|w_attn] + bias  (bf16 out)
    mfma_gemm<128, false, false, unsigned short><<<dim3(Mrows / 128, NQKV / 128), 256, 0, stream>>>(
        xnR, qkvT, qkvB, nullptr, F, NQKV, 256);
    // 3. deformable sampling + softmax + aggregation -> agg (reuses xn region)
    sample_kernel<<<Mrows / 4, 256, 0, stream>>>(F, refp, xnR);
    // 4. x2 = x + agg @ w_out + b_out -> d_out (f32)
    mfma_gemm<64, false, true, float><<<dim3(Mrows / 128, 256 / 64), 256, 0, stream>>>(
        xnR, woutT, b_out, x, out, 256, 256);
    // 5. LN2 -> y (bf16, reuses xn region)
    ln_kernel<unsigned short><<<Mrows, 256, 0, stream>>>(out, ln2_g, ln2_b, xnR);
    // 6. h = gelu(y @ w1 + b1) (bf16)
    mfma_gemm<128, true, false, unsigned short><<<dim3(Mrows / 128, 1024 / 128), 256, 0, stream>>>(
        xnR, w1T, b1, nullptr, h, 1024, 256);
    // 7. depthwise conv + gelu -> h2 (bf16)
    dwconv_kernel<<<Mrows / 4, 256, 0, stream>>>(h, wdwT, b_dw, h2);
    // 8. out = x2 + h2 @ w2 + b2 (f32, in-place residual)
    mfma_gemm<64, false, true, float><<<dim3(Mrows / 128, 256 / 64), 256, 0, stream>>>(
        h2, w2T, b2, out, out, 256, 1024);
}

// Round 10
// 132.376 us; speedup vs baseline: 1.3433x; 1.1144x over previous
//
#include <hip/hip_runtime.h>
#include <hip/hip_bf16.h>
#include <type_traits>

// Problem constants
constexpr int Bc = 2, Hc = 64, Wc = 128, Cc = 256;
constexpr int HEADS = 8, KPT = 9, HIDDEN = 1024;
constexpr int HD = Cc / HEADS;           // 32
constexpr int NPIX = Hc * Wc;            // 8192
constexpr int Mrows = Bc * NPIX;         // 16384
constexpr int NQKV = 512;                // 256 (v) + 144 (off) + 72 (attn) padded to 512

typedef __attribute__((ext_vector_type(4))) float f32x4;
typedef __attribute__((ext_vector_type(8))) short bf16x8;

__device__ __forceinline__ float bf2f(unsigned short u) {
    union { unsigned int i; float f; } c; c.i = ((unsigned int)u) << 16; return c.f;
}
__device__ __forceinline__ unsigned short f2bf(float f) {
    __hip_bfloat16 h = __float2bfloat16(f);
    return *reinterpret_cast<unsigned short*>(&h);
}
__device__ __forceinline__ float gelu_exact(float x) {
    return 0.5f * x * (1.0f + erff(x * 0.70710678118654752f));
}
__device__ __forceinline__ void gl2lds16(const void* g, void* l) {
    __builtin_amdgcn_global_load_lds(
        (const __attribute__((address_space(1))) unsigned int*)g,
        (__attribute__((address_space(3))) unsigned int*)l, 16, 0, 0);
}

// ---------------- LayerNorm over C=256: one WAVE per row, float4 loads (G13) ----------------
template<typename TO>
__global__ __launch_bounds__(256) void ln_kernel(const float* __restrict__ in,
        const float* __restrict__ g, const float* __restrict__ b,
        TO* __restrict__ out) {
    const int r = blockIdx.x * 4 + (threadIdx.x >> 6);
    const int l = threadIdx.x & 63;
    const size_t base = (size_t)r * Cc + l * 4;
    const float4 v = *reinterpret_cast<const float4*>(in + base);
    float s  = v.x + v.y + v.z + v.w;
    float s2 = v.x * v.x + v.y * v.y + v.z * v.z + v.w * v.w;
    #pragma unroll
    for (int o = 32; o > 0; o >>= 1) { s += __shfl_down(s, o); s2 += __shfl_down(s2, o); }
    s = __shfl(s, 0); s2 = __shfl(s2, 0);
    const float mean = s * (1.0f / Cc);
    const float var  = s2 * (1.0f / Cc) - mean * mean;
    const float rstd = rsqrtf(var + 1e-5f);
    const float4 gv = *reinterpret_cast<const float4*>(g + l * 4);
    const float4 bv = *reinterpret_cast<const float4*>(b + l * 4);
    const float o0 = (v.x - mean) * rstd * gv.x + bv.x;
    const float o1 = (v.y - mean) * rstd * gv.y + bv.y;
    const float o2 = (v.z - mean) * rstd * gv.z + bv.z;
    const float o3 = (v.w - mean) * rstd * gv.w + bv.w;
    if constexpr (std::is_same<TO, float>::value) {
        *reinterpret_cast<float4*>(out + base) = make_float4(o0, o1, o2, o3);
    } else {
        ushort4 o;
        o.x = f2bf(o0); o.y = f2bf(o1); o.z = f2bf(o2); o.w = f2bf(o3);
        *reinterpret_cast<ushort4*>(out + base) = o;
    }
}

// ---------------- Weight prep: f32 [K,N] -> bf16 [N,K] (transposed), QKV fused+padded ----
// Also transposes depthwise weights [1024][9] -> [9][1024] f32 for coalesced loads.
__global__ __launch_bounds__(256) void prep_weights(
        const float* __restrict__ w_v, const float* __restrict__ b_v,
        const float* __restrict__ w_off, const float* __restrict__ b_off,
        const float* __restrict__ w_attn, const float* __restrict__ b_attn,
        const float* __restrict__ w_out, const float* __restrict__ w1,
        const float* __restrict__ w2, const float* __restrict__ w_dw,
        unsigned short* __restrict__ qkvT, float* __restrict__ qkvB,
        unsigned short* __restrict__ woutT, unsigned short* __restrict__ w1T,
        unsigned short* __restrict__ w2T, float* __restrict__ wdwT) {
    const int blk = blockIdx.x;
    const int t = threadIdx.x;
    if (blk < NQKV) {                      // qkvT row n, K=256
        const int n = blk;
        float val = 0.0f;
        if (n < 256)       val = w_v[t * 256 + n];
        else if (n < 400)  val = w_off[t * 144 + (n - 256)];
        else if (n < 472)  val = w_attn[t * 72 + (n - 400)];
        qkvT[n * 256 + t] = f2bf(val);
        if (t == 0) {
            float bv = 0.0f;
            if (n < 256)      bv = b_v[n];
            else if (n < 400) bv = b_off[n - 256];
            else if (n < 472) bv = b_attn[n - 400];
            qkvB[n] = bv;
        }
    } else if (blk < NQKV + 256) {         // woutT row n, K=256
        const int n = blk - NQKV;
        woutT[n * 256 + t] = f2bf(w_out[t * 256 + n]);
    } else if (blk < NQKV + 256 + 1024) {  // w1T row n, K=256
        const int n = blk - (NQKV + 256);
        w1T[n * 256 + t] = f2bf(w1[t * 1024 + n]);
    } else if (blk < NQKV + 256 + 1024 + 256) { // w2T row n, K=1024
        const int n = blk - (NQKV + 256 + 1024);
        #pragma unroll
        for (int k = t; k < 1024; k += 256)
            w2T[n * 1024 + k] = f2bf(w2[k * 256 + n]);
    } else {                               // wdwT row j (9 rows)
        const int j = blk - (NQKV + 256 + 1024 + 256);
        #pragma unroll
        for (int c = t; c < HIDDEN; c += 256)
            wdwT[j * HIDDEN + c] = w_dw[c * 9 + j];
    }
}

// ---------------- bf16 MFMA GEMM: Out[M,N] = A[M,K] @ BT[N,K]^T + bias ----------------
// Tile 128 x BN, BK=64, **512 threads (8 waves)** for 4 waves/SIMD at 2 blocks/CU
// (R9 occupancy 15-21% with 4-wave blocks left every barrier with 0 runnable waves).
// Wave grid: BN=128 -> 2x4 (wave=64x32), BN=64 -> 4x2 (wave=32x32).
// Grid: blockIdx.x = row panel (fastest) -> same-row-panel blocks share one XCD L2.
// K-loop: counted-vmcnt 2-tile-ahead pipeline (T4). Epilogue: C-tile staged in the
// (now dead) LDS, then full-sector write-back (R9: cut WRITE 2-4x amplification).
template<int BN, bool GELU, bool RESID, typename TO>
__global__ __launch_bounds__(512) void mfma_gemm(
        const unsigned short* __restrict__ A,   // [M,K] bf16
        const unsigned short* __restrict__ BT,  // [N,K] bf16
        const float* __restrict__ bias,         // [N]
        const float* __restrict__ resid,        // [M,N] f32 (if RESID)
        TO* __restrict__ Out,                   // [M,N]
        int N, int K) {
    constexpr int WCOLS = (BN == 128) ? 4 : 2;  // waves along N
    constexpr int WROWS = 8 / WCOLS;            // waves along M
    constexpr int MI = 128 / (WROWS * 16);      // 16-row fragments per wave
    constexpr int NI = BN / (WCOLS * 16);       // 16-col fragments per wave
    constexpr int ACH = 2;                      // A chunks staged per wave (16 total)
    constexpr int BCH = (BN / 8) / 8;           // B chunks per wave (2 or 1)
    constexpr int LA = ACH + BCH;               // per-wave loads per stage
    constexpr int BUFB = 16384 + BN * 128;      // A tile 16 KB + B tile
    __shared__ __align__(16) char lds[2 * BUFB];
    const int t = threadIdx.x;
    const int w = t >> 6;
    const int l = t & 63;
    const int row0 = blockIdx.x * 128;
    const int col0 = blockIdx.y * BN;
    const int wr = (w / WCOLS) * (MI * 16);     // wave row offset in tile
    const int wc = (w % WCOLS) * (NI * 16);     // wave col offset in tile

    // staging geometry: chunk = 8 rows x 64 cols (1024 B); lane l -> row c*8+l/8,
    // 16B slot (l%8); source slot is XOR-swizzled so LDS holds swizzled layout.
    const int srow = l >> 3;
    const int selem = ((l & 7) ^ srow) * 8;     // element offset of this lane's 16B

    auto stage = [&](char* buf, int k0) {
        unsigned short* As_ = (unsigned short*)buf;
        unsigned short* Bs_ = (unsigned short*)(buf + 16384);
        #pragma unroll
        for (int i = 0; i < ACH; ++i) {         // A tile: 16 chunks, 2 per wave
            const int c = w + i * 8;
            const int row = c * 8 + srow;
            gl2lds16(A + (size_t)(row0 + row) * K + k0 + selem, As_ + c * 512);
        }
        #pragma unroll
        for (int i = 0; i < BCH; ++i) {         // B tile: BN/8 chunks
            const int c = w + i * 8;
            const int row = c * 8 + srow;
            gl2lds16(BT + (size_t)(col0 + row) * K + k0 + selem, Bs_ + c * 512);
        }
    };

    f32x4 acc[MI][NI] = {};
    const int nt = K / 64;

    // prologue: stage tiles 0 and 1 (2-deep pipeline)
    stage(lds, 0);
    stage(lds + BUFB, 64);

    for (int tt = 0; tt < nt; ++tt) {
        // wait for tile tt's DMA only; tile tt+1's LA loads may stay outstanding
        if (tt + 1 < nt) {
            if constexpr (LA == 4) asm volatile("s_waitcnt vmcnt(4)" ::: "memory");
            else                   asm volatile("s_waitcnt vmcnt(3)" ::: "memory");
        } else {
            asm volatile("s_waitcnt vmcnt(0)" ::: "memory");
        }
        __builtin_amdgcn_s_barrier();
        __builtin_amdgcn_sched_barrier(0);

        const char* Ab = lds + (size_t)(tt & 1) * BUFB;
        const char* Bb = Ab + 16384;
        #pragma unroll
        for (int ks = 0; ks < 2; ++ks) {
            const int kb = ks * 64 + (l >> 4) * 16;   // byte offset within 128B row
            bf16x8 af[MI], bfr[NI];
            #pragma unroll
            for (int mi = 0; mi < MI; ++mi) {
                const int row = wr + mi * 16 + (l & 15);
                af[mi] = *(const bf16x8*)(Ab + row * 128 + (kb ^ ((row & 7) << 4)));
            }
            #pragma unroll
            for (int ni = 0; ni < NI; ++ni) {
                const int row = wc + ni * 16 + (l & 15);
                bfr[ni] = *(const bf16x8*)(Bb + row * 128 + (kb ^ ((row & 7) << 4)));
            }
            #pragma unroll
            for (int mi = 0; mi < MI; ++mi)
                #pragma unroll
                for (int ni = 0; ni < NI; ++ni)
                    acc[mi][ni] = __builtin_amdgcn_mfma_f32_16x16x32_bf16(
                        af[mi], bfr[ni], acc[mi][ni], 0, 0, 0);
        }
        // all waves done reading buf[tt&1] before it is re-staged
        __builtin_amdgcn_s_barrier();
        __builtin_amdgcn_sched_barrier(0);
        if (tt + 2 < nt) stage(lds + (size_t)(tt & 1) * BUFB, (tt + 2) * 64);
    }

    // ---- epilogue phase 1: stage C-tile into LDS (256 B per row, row-XOR swizzle) ----
    // MFMA C/D layout: col=l&15, row=(l>>4)*4+reg (guide §3, m89-verified)
    const int lrow = (l >> 4) * 4;
    const int lcol = l & 15;
    #pragma unroll
    for (int ni = 0; ni < NI; ++ni) {
        const int col = wc + ni * 16 + lcol;            // tile-relative col
        const float bb = bias[col0 + col];
        #pragma unroll
        for (int mi = 0; mi < MI; ++mi) {
            #pragma unroll
            for (int r = 0; r < 4; ++r) {
                const int row = wr + mi * 16 + lrow + r;
                float v = acc[mi][ni][r] + bb;
                if constexpr (GELU) v = gelu_exact(v);
                if constexpr (std::is_same<TO, unsigned short>::value) {
                    *(unsigned short*)(lds + row * 256 + ((col * 2) ^ ((row & 7) << 4))) = f2bf(v);
                } else {
                    *(float*)(lds + row * 256 + ((col * 4) ^ ((row & 7) << 4))) = v;
                }
            }
        }
    }
    __syncthreads();
    // ---- epilogue phase 2: full-sector write-back ----
    // 16 lanes cover one complete 256 B row; every 64 B sector from one instruction.
    const int ck = t & 15;                    // 16 B chunk within the 256 B row
    #pragma unroll
    for (int it = 0; it < 4; ++it) {
        const int row = (t >> 4) + it * 32;
        const int bo = ck * 16;
        if constexpr (std::is_same<TO, unsigned short>::value) {
            const int4 val = *(const int4*)(lds + row * 256 + (bo ^ ((row & 7) << 4)));
            *(int4*)(Out + (size_t)(row0 + row) * N + col0 + bo / 2) = val;
        } else {
            float4 val = *(const float4*)(lds + row * 256 + (bo ^ ((row & 7) << 4)));
            if constexpr (RESID) {
                const float4 rv = *(const float4*)(resid + (size_t)(row0 + row) * N + col0 + bo / 4);
                val.x += rv.x; val.y += rv.y; val.z += rv.z; val.w += rv.w;
            }
            *(float4*)((float*)Out + (size_t)(row0 + row) * N + col0 + bo / 4) = val;
        }
    }
}

// ---------------- Deformable sampling + softmax + aggregation (bf16 in/out) ----------------
// F = fused QKV buffer [M, 512]: cols 0-255 v, 256-399 offsets, 400-471 attn logits.
// 4 pixels per block (one wave each); lane tl: head = tl>>3, quad = tl&7 owns 4 channels.
// XCD-chunked block swizzle keeps spatially-neighboring gathers in one XCD's L2
// (R5/R6 FETCH 49 MB vs ~17 ideal: each XCD was re-fetching the same v region).
__global__ __launch_bounds__(256) void sample_kernel(const unsigned short* __restrict__ F,
        const float* __restrict__ refp, unsigned short* __restrict__ agg) {
    constexpr int PPB = 4;                       // pixels per block
    constexpr int nblk = Mrows / PPB;            // 4096
    const int bid = blockIdx.x;
    const int qi = (bid & 7) * (nblk / 8) + (bid >> 3);   // 4096 % 8 == 0 -> bijective
    const int m0 = qi * PPB;
    const int b = m0 / NPIX;
    const int pix0 = m0 - b * NPIX;
    const int t = threadIdx.x;
    __shared__ int4   s_idx[PPB][72];
    __shared__ float4 s_w[PPB][72];
    __shared__ float  s_lg[PPB][72];

    // phase 1: coords + bilinear corners/weights + logits (288 items on 256 threads)
    for (int idx = t; idx < PPB * 72; idx += 256) {
        const int p = idx / 72, hk = idx - p * 72;
        const int head = hk / 9, k = hk - head * 9;
        const int m = m0 + p, pix = pix0 + p;
        const size_t fb = (size_t)m * NQKV;
        const unsigned int ou = *(const unsigned int*)(F + fb + 256 + head * 18 + k * 2);
        const float ox = __uint_as_float(ou << 16);
        const float oy = __uint_as_float(ou & 0xffff0000u);
        const float2 rr = *(const float2*)(refp + ((size_t)pix * KPT + k) * 2);
        const float cx = (rr.x + ox + 1.0f) * 0.5f * (Wc - 1);
        const float cy = (rr.y + oy + 1.0f) * 0.5f * (Hc - 1);
        const float fx = floorf(cx), fy = floorf(cy);
        const float wx = cx - fx, wy = cy - fy;
        const int x0 = min(max((int)fx, 0), Wc - 1);
        const int x1 = min(max((int)fx + 1, 0), Wc - 1);
        const int y0 = min(max((int)fy, 0), Hc - 1);
        const int y1 = min(max((int)fy + 1, 0), Hc - 1);
        s_idx[p][hk] = make_int4(y0 * Wc + x0, y0 * Wc + x1, y1 * Wc + x0, y1 * Wc + x1);
        s_w[p][hk] = make_float4((1.0f - wy) * (1.0f - wx), (1.0f - wy) * wx,
                                 wy * (1.0f - wx), wy * wx);
        s_lg[p][hk] = bf2f(F[fb + 400 + hk]);
    }
    __syncthreads();
    // phase 2: softmax over k per (p, head); premultiply attn into corner weights
    for (int idx = t; idx < PPB * 72; idx += 256) {
        const int p = idx / 72, hk = idx - p * 72;
        const int h9 = (hk / 9) * 9;
        float mx = -1e30f;
        #pragma unroll
        for (int k = 0; k < 9; ++k) mx = fmaxf(mx, s_lg[p][h9 + k]);
        float sm = 0.0f;
        #pragma unroll
        for (int k = 0; k < 9; ++k) sm += __expf(s_lg[p][h9 + k] - mx);
        const float a = __expf(s_lg[p][hk] - mx) / sm;
        float4 w = s_w[p][hk];
        w.x *= a; w.y *= a; w.z *= a; w.w *= a;
        s_w[p][hk] = w;
    }
    __syncthreads();
    // phase 3: gather-accumulate, 4 channels per lane
    const int p = t >> 6, tl = t & 63;
    const int head = tl >> 3, dq = tl & 7;
    const unsigned short* vb = F + (size_t)b * NPIX * NQKV + head * HD + dq * 4;
    float a0 = 0.f, a1 = 0.f, a2 = 0.f, a3 = 0.f;
    #pragma unroll
    for (int k = 0; k < 9; ++k) {
        const int hk = head * 9 + k;
        const int4   ix = s_idx[p][hk];
        const float4 ww = s_w[p][hk];
        {
            const uint2 u = *(const uint2*)(vb + (size_t)ix.x * NQKV);
            a0 += __uint_as_float(u.x << 16) * ww.x;
            a1 += __uint_as_float(u.x & 0xffff0000u) * ww.x;
            a2 += __uint_as_float(u.y << 16) * ww.x;
            a3 += __uint_as_float(u.y & 0xffff0000u) * ww.x;
        }
        {
            const uint2 u = *(const uint2*)(vb + (size_t)ix.y * NQKV);
            a0 += __uint_as_float(u.x << 16) * ww.y;
            a1 += __uint_as_float(u.x & 0xffff0000u) * ww.y;
            a2 += __uint_as_float(u.y << 16) * ww.y;
            a3 += __uint_as_float(u.y & 0xffff0000u) * ww.y;
        }
        {
            const uint2 u = *(const uint2*)(vb + (size_t)ix.z * NQKV);
            a0 += __uint_as_float(u.x << 16) * ww.z;
            a1 += __uint_as_float(u.x & 0xffff0000u) * ww.z;
            a2 += __uint_as_float(u.y << 16) * ww.z;
            a3 += __uint_as_float(u.y & 0xffff0000u) * ww.z;
        }
        {
            const uint2 u = *(const uint2*)(vb + (size_t)ix.w * NQKV);
            a0 += __uint_as_float(u.x << 16) * ww.w;
            a1 += __uint_as_float(u.x & 0xffff0000u) * ww.w;
            a2 += __uint_as_float(u.y << 16) * ww.w;
            a3 += __uint_as_float(u.y & 0xffff0000u) * ww.w;
        }
    }
    ushort4 o;
    o.x = f2bf(a0); o.y = f2bf(a1); o.z = f2bf(a2); o.w = f2bf(a3);
    *reinterpret_cast<ushort4*>(agg + (size_t)(m0 + p) * Cc + tl * 4) = o;
}

// ---------------- Depthwise 3x3 conv (circular W, zero H) + GELU, bf16 in/out ----------------
// Quad-of-pixels per block: each block computes 4 consecutive x positions for all 1024
// channels; thread t owns channels [4t,4t+4) for all 4 outputs.
__global__ __launch_bounds__(256) void dwconv_kernel(const unsigned short* __restrict__ h,
        const float* __restrict__ wdwT, const float* __restrict__ bdw,
        unsigned short* __restrict__ h2) {
    constexpr int NQ = 4;                     // x-positions per block
    constexpr int nblk = Mrows / NQ;          // 4096
    const int bid = blockIdx.x;
    const int qi = (bid & 7) * (nblk / 8) + (bid >> 3);   // XCD-chunked swizzle (4096 % 8 == 0)
    const int m0 = qi * NQ;                   // quad never crosses a row (Wc % NQ == 0)
    const int b = m0 / NPIX;
    const int pix0 = m0 - b * NPIX;
    const int y = pix0 / Wc, x0 = pix0 - y * Wc;
    const int t = threadIdx.x;
    const int c0 = t * 4;

    float wreg[9][4];
    #pragma unroll
    for (int j = 0; j < 9; ++j) {
        const float4 wv = *reinterpret_cast<const float4*>(wdwT + j * HIDDEN + c0);
        wreg[j][0] = wv.x; wreg[j][1] = wv.y; wreg[j][2] = wv.z; wreg[j][3] = wv.w;
    }

    float acc[NQ][4] = {};
    #pragma unroll
    for (int dy = -1; dy <= 1; ++dy) {
        const int yy = y + dy;
        if (yy < 0 || yy >= Hc) continue;     // zero pad along height (block-uniform branch)
        const size_t rowbase = ((size_t)b * NPIX + (size_t)yy * Wc) * HIDDEN + c0;
        #pragma unroll
        for (int j = 0; j < NQ + 2; ++j) {    // columns x0-1 .. x0+NQ (circular)
            const int xx = (x0 + j - 1 + Wc) & (Wc - 1);
            const ushort4 hv = *reinterpret_cast<const ushort4*>(h + rowbase + (size_t)xx * HIDDEN);
            const float f0 = bf2f(hv.x), f1 = bf2f(hv.y), f2 = bf2f(hv.z), f3 = bf2f(hv.w);
            #pragma unroll
            for (int q = 0; q < NQ; ++q) {
                if (q >= j - 2 && q <= j) {   // folds to constants after unroll
                    const int wj = (dy + 1) * 3 + (j - q);
                    acc[q][0] += f0 * wreg[wj][0];
                    acc[q][1] += f1 * wreg[wj][1];
                    acc[q][2] += f2 * wreg[wj][2];
                    acc[q][3] += f3 * wreg[wj][3];
                }
            }
        }
    }
    const float4 bb = *reinterpret_cast<const float4*>(bdw + c0);
    #pragma unroll
    for (int q = 0; q < NQ; ++q) {
        ushort4 o;
        o.x = f2bf(gelu_exact(acc[q][0] + bb.x));
        o.y = f2bf(gelu_exact(acc[q][1] + bb.y));
        o.z = f2bf(gelu_exact(acc[q][2] + bb.z));
        o.w = f2bf(gelu_exact(acc[q][3] + bb.w));
        *reinterpret_cast<ushort4*>(h2 + (size_t)(m0 + q) * HIDDEN + c0) = o;
    }
}

extern "C" void kernel_launch(void* const* d_in, const int* in_sizes, int n_in,
                              void* d_out, int out_size, void* d_ws, size_t ws_size,
                              hipStream_t stream) {
    const float* x      = (const float*)d_in[0];
    const float* refp   = (const float*)d_in[1];
    const float* ln1_g  = (const float*)d_in[2];
    const float* ln1_b  = (const float*)d_in[3];
    const float* w_v    = (const float*)d_in[4];
    const float* b_v    = (const float*)d_in[5];
    const float* w_off  = (const float*)d_in[6];
    const float* b_off  = (const float*)d_in[7];
    const float* w_attn = (const float*)d_in[8];
    const float* b_attn = (const float*)d_in[9];
    const float* w_out  = (const float*)d_in[10];
    const float* b_out  = (const float*)d_in[11];
    const float* ln2_g  = (const float*)d_in[12];
    const float* ln2_b  = (const float*)d_in[13];
    const float* w1     = (const float*)d_in[14];
    const float* b1     = (const float*)d_in[15];
    const float* w_dw   = (const float*)d_in[16];
    const float* b_dw   = (const float*)d_in[17];
    const float* w2     = (const float*)d_in[18];
    const float* b2     = (const float*)d_in[19];
    float* out = (float*)d_out;

    // Workspace layout (bytes); lifetimes make the overlaps safe:
    //  [0,  8M): xn -> agg -> y          (bf16 [M,256], sequential reuse)
    //  [8, 24M): F fused qkv (bf16 [M,512]) — dead after sample_kernel
    //  [8, 40M): h (bf16 [M,1024])       — written after F is dead
    //  [40,72M): h2 (bf16 [M,1024])
    //  [72M,..): transposed bf16 weights + wdwT + fused qkv bias
    char* wsb = (char*)d_ws;
    unsigned short* xnR = (unsigned short*)(wsb);
    unsigned short* F   = (unsigned short*)(wsb + (8ull  << 20));
    unsigned short* h   = (unsigned short*)(wsb + (8ull  << 20));
    unsigned short* h2  = (unsigned short*)(wsb + (40ull << 20));
    size_t woff = 72ull << 20;
    unsigned short* qkvT = (unsigned short*)(wsb + woff); woff += (size_t)NQKV * 256 * 2;
    unsigned short* woutT= (unsigned short*)(wsb + woff); woff += 256 * 256 * 2;
    unsigned short* w1T  = (unsigned short*)(wsb + woff); woff += 1024 * 256 * 2;
    unsigned short* w2T  = (unsigned short*)(wsb + woff); woff += 256 * 1024 * 2;
    float*          wdwT = (float*)(wsb + woff);          woff += 9 * 1024 * 4;
    float*          qkvB = (float*)(wsb + woff);

    // 0. weight transpose/convert (independent of activations)
    prep_weights<<<NQKV + 256 + 1024 + 256 + 9, 256, 0, stream>>>(
        w_v, b_v, w_off, b_off, w_attn, b_attn, w_out, w1, w2, w_dw,
        qkvT, qkvB, woutT, w1T, w2T, wdwT);
    // 1. LN1 -> xn (bf16)
    ln_kernel<unsigned short><<<Mrows / 4, 256, 0, stream>>>(x, ln1_g, ln1_b, xnR);
    // 2. fused QKV GEMM: F = xn @ [w_v|w_off|w_attn] + bias  (bf16 out)
    mfma_gemm<128, false, false, unsigned short><<<dim3(Mrows / 128, NQKV / 128), 512, 0, stream>>>(
        xnR, qkvT, qkvB, nullptr, F, NQKV, 256);
    // 3. deformable sampling + softmax + aggregation -> agg (reuses xn region)
    sample_kernel<<<Mrows / 4, 256, 0, stream>>>(F, refp, xnR);
    // 4. x2 = x + agg @ w_out + b_out -> d_out (f32)
    mfma_gemm<64, false, true, float><<<dim3(Mrows / 128, 256 / 64), 512, 0, stream>>>(
        xnR, woutT, b_out, x, out, 256, 256);
    // 5. LN2 -> y (bf16, reuses xn region)
    ln_kernel<unsigned short><<<Mrows / 4, 256, 0, stream>>>(out, ln2_g, ln2_b, xnR);
    // 6. h = gelu(y @ w1 + b1) (bf16)
    mfma_gemm<128, true, false, unsigned short><<<dim3(Mrows / 128, 1024 / 128), 512, 0, stream>>>(
        xnR, w1T, b1, nullptr, h, 1024, 256);
    // 7. depthwise conv + gelu -> h2 (bf16)
    dwconv_kernel<<<Mrows / 4, 256, 0, stream>>>(h, wdwT, b_dw, h2);
    // 8. out = x2 + h2 @ w2 + b2 (f32, in-place residual)
    mfma_gemm<64, false, true, float><<<dim3(Mrows / 128, 256 / 64), 512, 0, stream>>>(
        h2, w2T, b2, out, out, 256, 1024);
}